// Round 1
// baseline (921.458 us; speedup 1.0000x reference)
//
#include <hip/hip_runtime.h>
#include <math.h>

#define N_NODES 100000
#define N_EDGES 1600000

// ---------------------------------------------------------------------------
// CSR build: count degrees, allocate rows (wave-aggregated atomic), scatter
// ---------------------------------------------------------------------------

__global__ void count_kernel(const int* __restrict__ ei, int* __restrict__ deg, int E) {
    int e = blockIdx.x * 256 + threadIdx.x;
    if (e < E) atomicAdd(&deg[ei[E + e]], 1);
}

__global__ void alloc_kernel(const int* __restrict__ deg, int* __restrict__ rowstart,
                             int* __restrict__ cursor, int* __restrict__ counter, int n) {
    int i = blockIdx.x * 256 + threadIdx.x;
    int lane = threadIdx.x & 63;
    int d = (i < n) ? deg[i] : 0;
    // wave-level inclusive prefix sum (avoid 100k atomics on one counter)
    int pre = d;
    #pragma unroll
    for (int off = 1; off < 64; off <<= 1) {
        int v = __shfl_up(pre, off, 64);
        if (lane >= off) pre += v;
    }
    int total = __shfl(pre, 63, 64);
    int base = 0;
    if (lane == 63) base = atomicAdd(counter, total);
    base = __shfl(base, 63, 64);
    int start = base + pre - d;
    if (i < n) { rowstart[i] = start; cursor[i] = start; }
}

__global__ void scatter_kernel(const int* __restrict__ ei, int* __restrict__ cursor,
                               int* __restrict__ csr_src, int E) {
    int e = blockIdx.x * 256 + threadIdx.x;
    if (e < E) {
        int d = ei[E + e];
        int slot = atomicAdd(&cursor[d], 1);
        csr_src[slot] = ei[e];
    }
}

// ---------------------------------------------------------------------------
// GEMM1: h1 = x[N,256] @ W1[256,128]; fused a1s/a1d attention dots.
// block 128 threads: 32 rows/block; thread = 4 cols x 8 rows.
// ---------------------------------------------------------------------------
__global__ void __launch_bounds__(128) gemm1_kernel(
        const float* __restrict__ x, const float4* __restrict__ W1,
        const float* __restrict__ att_s, const float* __restrict__ att_d,
        float* __restrict__ h1, float* __restrict__ a1s, float* __restrict__ a1d) {
    __shared__ float xs[32][256];
    const int t = threadIdx.x;
    const int row0 = blockIdx.x * 32;   // 100000 % 32 == 0 -> always full
    {
        const float4* x4 = (const float4*)(x + (size_t)row0 * 256);
        float4* s4 = (float4*)xs;
        #pragma unroll
        for (int i = 0; i < 16; i++) s4[t + i * 128] = x4[t + i * 128];
    }
    __syncthreads();
    const int cg = t & 31;           // cols 4*cg .. 4*cg+3
    const int rbase = (t >> 5) * 8;  // 8 rows
    float4 acc[8];
    #pragma unroll
    for (int r = 0; r < 8; r++) acc[r] = make_float4(0.f, 0.f, 0.f, 0.f);
    #pragma unroll 4
    for (int k = 0; k < 256; k++) {
        float4 w = W1[k * 32 + cg];
        #pragma unroll
        for (int r = 0; r < 8; r++) {
            float xv = xs[rbase + r][k];
            acc[r].x += xv * w.x; acc[r].y += xv * w.y;
            acc[r].z += xv * w.z; acc[r].w += xv * w.w;
        }
    }
    float4 asw = ((const float4*)att_s)[cg];
    float4 adw = ((const float4*)att_d)[cg];
    const int h = cg >> 2;  // head = (4*cg)/16
    #pragma unroll
    for (int r = 0; r < 8; r++) {
        int row = row0 + rbase + r;
        *(float4*)(h1 + (size_t)row * 128 + 4 * cg) = acc[r];
        float ps = acc[r].x * asw.x + acc[r].y * asw.y + acc[r].z * asw.z + acc[r].w * asw.w;
        float pd = acc[r].x * adw.x + acc[r].y * adw.y + acc[r].z * adw.z + acc[r].w * adw.w;
        ps += __shfl_xor(ps, 1, 64); ps += __shfl_xor(ps, 2, 64);
        pd += __shfl_xor(pd, 1, 64); pd += __shfl_xor(pd, 2, 64);
        if ((cg & 3) == 0) { a1s[row * 8 + h] = ps; a1d[row * 8 + h] = pd; }
    }
}

// ---------------------------------------------------------------------------
// agg1: one wave per dst node. Online softmax over CSR edge list.
// lane: head = lane>>3, channel pair = (lane&7)*2  ->  col j = 2*lane.
// Fused: /denom, +b1, ELU. Writes h2in[N,128].
// ---------------------------------------------------------------------------
__global__ void __launch_bounds__(256) agg1_kernel(
        const float* __restrict__ h1, const float* __restrict__ a1s,
        const float* __restrict__ a1d, const int* __restrict__ rowstart,
        const int* __restrict__ deg, const int* __restrict__ csr_src,
        const float* __restrict__ b1, float* __restrict__ h2in, int n) {
    const int lane = threadIdx.x & 63;
    const int node = blockIdx.x * 4 + (threadIdx.x >> 6);
    if (node >= n) return;
    const int h = lane >> 3;
    const int start = rowstart[node];
    const int d = deg[node];
    const float ad = a1d[node * 8 + h];
    float m = -INFINITY, l = 0.f, acc0 = 0.f, acc1 = 0.f;
    for (int i = 0; i < d; i++) {
        int s = csr_src[start + i];
        float logit = a1s[s * 8 + h] + ad;
        logit = (logit > 0.f) ? logit : 0.2f * logit;
        float nm = fmaxf(m, logit);
        float scale = expf(m - nm);     // first iter: exp(-inf)=0
        float e = expf(logit - nm);
        float2 hv = *(const float2*)(h1 + (size_t)s * 128 + lane * 2);
        l = l * scale + e;
        acc0 = acc0 * scale + e * hv.x;
        acc1 = acc1 * scale + e * hv.y;
        m = nm;
    }
    float inv = 1.f / (l + 1e-16f);
    float v0 = acc0 * inv + b1[lane * 2];
    float v1 = acc1 * inv + b1[lane * 2 + 1];
    v0 = (v0 > 0.f) ? v0 : (expm1f(v0));
    v1 = (v1 > 0.f) ? v1 : (expm1f(v1));
    *(float2*)(h2in + (size_t)node * 128 + lane * 2) = make_float2(v0, v1);
}

// ---------------------------------------------------------------------------
// GEMM2: t2 = h2in[N,128] @ W2[128,64]; fused a2s/a2d (length-64 dots).
// block 128 threads: 64 rows/block; thread = 4 cols x 8 rows.
// ---------------------------------------------------------------------------
__global__ void __launch_bounds__(128) gemm2_kernel(
        const float* __restrict__ h2in, const float4* __restrict__ W2,
        const float* __restrict__ att_s, const float* __restrict__ att_d,
        float* __restrict__ t2, float* __restrict__ a2s, float* __restrict__ a2d, int n) {
    __shared__ float xs[64][128];
    const int t = threadIdx.x;
    const int row0 = blockIdx.x * 64;
    {
        float4* s4 = (float4*)xs;
        #pragma unroll
        for (int i = 0; i < 16; i++) {
            int idx = t + i * 128;          // float4 index; row = idx/32
            int row = row0 + (idx >> 5);
            s4[idx] = (row < n) ? ((const float4*)h2in)[(size_t)row * 32 + (idx & 31)]
                                : make_float4(0.f, 0.f, 0.f, 0.f);
        }
    }
    __syncthreads();
    const int cg = t & 15;            // cols 4*cg .. 4*cg+3
    const int rbase = (t >> 4) * 8;   // 8 rows
    float4 acc[8];
    #pragma unroll
    for (int r = 0; r < 8; r++) acc[r] = make_float4(0.f, 0.f, 0.f, 0.f);
    #pragma unroll 4
    for (int k = 0; k < 128; k++) {
        float4 w = W2[k * 16 + cg];
        #pragma unroll
        for (int r = 0; r < 8; r++) {
            float xv = xs[rbase + r][k];
            acc[r].x += xv * w.x; acc[r].y += xv * w.y;
            acc[r].z += xv * w.z; acc[r].w += xv * w.w;
        }
    }
    float4 asw = ((const float4*)att_s)[cg];
    float4 adw = ((const float4*)att_d)[cg];
    #pragma unroll
    for (int r = 0; r < 8; r++) {
        int row = row0 + rbase + r;
        if (row >= n) continue;
        *(float4*)(t2 + (size_t)row * 64 + 4 * cg) = acc[r];
        float ps = acc[r].x * asw.x + acc[r].y * asw.y + acc[r].z * asw.z + acc[r].w * asw.w;
        float pd = acc[r].x * adw.x + acc[r].y * adw.y + acc[r].z * adw.z + acc[r].w * adw.w;
        ps += __shfl_xor(ps, 1, 64); ps += __shfl_xor(ps, 2, 64);
        ps += __shfl_xor(ps, 4, 64); ps += __shfl_xor(ps, 8, 64);
        pd += __shfl_xor(pd, 1, 64); pd += __shfl_xor(pd, 2, 64);
        pd += __shfl_xor(pd, 4, 64); pd += __shfl_xor(pd, 8, 64);
        if (cg == 0) { a2s[row] = ps; a2d[row] = pd; }
    }
}

// ---------------------------------------------------------------------------
// agg2: one wave per dst node, lane = channel (64). Online softmax +
// fused bias + log_softmax across the wave. Writes final output.
// ---------------------------------------------------------------------------
__global__ void __launch_bounds__(256) agg2_kernel(
        const float* __restrict__ t2, const float* __restrict__ a2s,
        const float* __restrict__ a2d, const int* __restrict__ rowstart,
        const int* __restrict__ deg, const int* __restrict__ csr_src,
        const float* __restrict__ b2, float* __restrict__ out, int n) {
    const int lane = threadIdx.x & 63;
    const int node = blockIdx.x * 4 + (threadIdx.x >> 6);
    if (node >= n) return;
    const int start = rowstart[node];
    const int d = deg[node];
    const float ad = a2d[node];
    float m = -INFINITY, l = 0.f, acc = 0.f;
    for (int i = 0; i < d; i++) {
        int s = csr_src[start + i];
        float logit = a2s[s] + ad;
        logit = (logit > 0.f) ? logit : 0.2f * logit;
        float nm = fmaxf(m, logit);
        float scale = expf(m - nm);
        float e = expf(logit - nm);
        float hv = t2[(size_t)s * 64 + lane];
        l = l * scale + e;
        acc = acc * scale + e * hv;
        m = nm;
    }
    float v = acc / (l + 1e-16f) + b2[lane];
    // log_softmax over the 64 lanes
    float mx = v;
    #pragma unroll
    for (int off = 32; off >= 1; off >>= 1) mx = fmaxf(mx, __shfl_xor(mx, off, 64));
    float ex = expf(v - mx);
    float s2 = ex;
    #pragma unroll
    for (int off = 32; off >= 1; off >>= 1) s2 += __shfl_xor(s2, off, 64);
    out[(size_t)node * 64 + lane] = v - mx - logf(s2);
}

// ---------------------------------------------------------------------------

extern "C" void kernel_launch(void* const* d_in, const int* in_sizes, int n_in,
                              void* d_out, int out_size, void* d_ws, size_t ws_size,
                              hipStream_t stream) {
    const float* x     = (const float*)d_in[0];
    const int*   ei    = (const int*)d_in[1];
    const float* W1    = (const float*)d_in[2];
    const float* att1s = (const float*)d_in[3];
    const float* att1d = (const float*)d_in[4];
    const float* b1    = (const float*)d_in[5];
    const float* W2    = (const float*)d_in[6];
    const float* att2s = (const float*)d_in[7];
    const float* att2d = (const float*)d_in[8];
    const float* b2    = (const float*)d_in[9];
    float* out = (float*)d_out;

    const int N = N_NODES, E = N_EDGES;

    // workspace carve-up (256B aligned slices)
    char* p = (char*)d_ws;
    auto take = [&](size_t bytes) {
        char* r = p;
        p += (bytes + 255) & ~(size_t)255;
        return (void*)r;
    };
    int*   deg      = (int*)take((size_t)N * 4);
    int*   rowstart = (int*)take((size_t)N * 4);
    int*   cursor   = (int*)take((size_t)N * 4);
    int*   counter  = (int*)take(256);
    int*   csr_src  = (int*)take((size_t)E * 4);
    float* h1       = (float*)take((size_t)N * 128 * 4);  // reused as t2 later
    float* a1s      = (float*)take((size_t)N * 8 * 4);    // reused as a2s
    float* a1d      = (float*)take((size_t)N * 8 * 4);    // reused as a2d
    float* h2in     = (float*)take((size_t)N * 128 * 4);
    float* t2  = h1;
    float* a2s = a1s;
    float* a2d = a1d;

    hipMemsetAsync(deg, 0, (size_t)N * 4, stream);
    hipMemsetAsync(counter, 0, 4, stream);

    count_kernel<<<(E + 255) / 256, 256, 0, stream>>>(ei, deg, E);
    alloc_kernel<<<(N + 255) / 256, 256, 0, stream>>>(deg, rowstart, cursor, counter, N);
    scatter_kernel<<<(E + 255) / 256, 256, 0, stream>>>(ei, cursor, csr_src, E);

    gemm1_kernel<<<N / 32, 128, 0, stream>>>(x, (const float4*)W1, att1s, att1d, h1, a1s, a1d);
    agg1_kernel<<<(N + 3) / 4, 256, 0, stream>>>(h1, a1s, a1d, rowstart, deg, csr_src, b1, h2in, N);
    gemm2_kernel<<<(N + 63) / 64, 128, 0, stream>>>(h2in, (const float4*)W2, att2s, att2d, t2, a2s, a2d, N);
    agg2_kernel<<<(N + 3) / 4, 256, 0, stream>>>(t2, a2s, a2d, rowstart, deg, csr_src, b2, out, N);
}

// Round 2
// 808.759 us; speedup vs baseline: 1.1393x; 1.1393x over previous
//
#include <hip/hip_runtime.h>
#include <math.h>

#define N_NODES 100000
#define N_EDGES 1600000

__device__ __forceinline__ float lrelu(float v) {
    return (v > 0.f) ? v : 0.2f * v;
}

// ---------------------------------------------------------------------------
// CSR build: count degrees, allocate rows (wave-aggregated atomic)
// ---------------------------------------------------------------------------

__global__ void count_kernel(const int* __restrict__ ei, int* __restrict__ deg, int E) {
    int e = blockIdx.x * 256 + threadIdx.x;
    if (e < E) atomicAdd(&deg[ei[E + e]], 1);
}

__global__ void alloc_kernel(const int* __restrict__ deg, int* __restrict__ rowstart,
                             int* __restrict__ cursor, int* __restrict__ counter, int n) {
    int i = blockIdx.x * 256 + threadIdx.x;
    int lane = threadIdx.x & 63;
    int d = (i < n) ? deg[i] : 0;
    int pre = d;
    #pragma unroll
    for (int off = 1; off < 64; off <<= 1) {
        int v = __shfl_up(pre, off, 64);
        if (lane >= off) pre += v;
    }
    int total = __shfl(pre, 63, 64);
    int base = 0;
    if (lane == 63) base = atomicAdd(counter, total);
    base = __shfl(base, 63, 64);
    int start = base + pre - d;
    if (i < n) { rowstart[i] = start; cursor[i] = start; }
}

// ---------------------------------------------------------------------------
// Scatter fused with layer-1 edge weights: per edge, allocate CSR slot and
// write exp(lrelu(a1s[src]+a1d[dst])) for all 8 heads in slot order.
// (No max subtraction: logits are ~N(0,2.8); exp overflow needs logit>88.)
// ---------------------------------------------------------------------------
__global__ void scatter_w1_kernel(const int* __restrict__ ei, int* __restrict__ cursor,
                                  int* __restrict__ csr_src, int* __restrict__ csr_dst,
                                  const float* __restrict__ a1s, const float* __restrict__ a1d,
                                  float* __restrict__ ew1, int E) {
    int e = blockIdx.x * 256 + threadIdx.x;
    if (e >= E) return;
    int s = ei[e];
    int d = ei[E + e];
    int slot = atomicAdd(&cursor[d], 1);
    csr_src[slot] = s;
    csr_dst[slot] = d;
    float4 s0 = *(const float4*)(a1s + (size_t)s * 8);
    float4 s1 = *(const float4*)(a1s + (size_t)s * 8 + 4);
    float4 d0 = *(const float4*)(a1d + (size_t)d * 8);
    float4 d1 = *(const float4*)(a1d + (size_t)d * 8 + 4);
    float4 w0, w1;
    w0.x = expf(lrelu(s0.x + d0.x)); w0.y = expf(lrelu(s0.y + d0.y));
    w0.z = expf(lrelu(s0.z + d0.z)); w0.w = expf(lrelu(s0.w + d0.w));
    w1.x = expf(lrelu(s1.x + d1.x)); w1.y = expf(lrelu(s1.y + d1.y));
    w1.z = expf(lrelu(s1.z + d1.z)); w1.w = expf(lrelu(s1.w + d1.w));
    *(float4*)(ew1 + (size_t)slot * 8) = w0;
    *(float4*)(ew1 + (size_t)slot * 8 + 4) = w1;
}

// ---------------------------------------------------------------------------
// GEMM1: h1 = x[N,256] @ W1[256,128]; fused a1s/a1d attention dots.
// ---------------------------------------------------------------------------
__global__ void __launch_bounds__(128) gemm1_kernel(
        const float* __restrict__ x, const float4* __restrict__ W1,
        const float* __restrict__ att_s, const float* __restrict__ att_d,
        float* __restrict__ h1, float* __restrict__ a1s, float* __restrict__ a1d) {
    __shared__ float xs[32][256];
    const int t = threadIdx.x;
    const int row0 = blockIdx.x * 32;   // 100000 % 32 == 0
    {
        const float4* x4 = (const float4*)(x + (size_t)row0 * 256);
        float4* s4 = (float4*)xs;
        #pragma unroll
        for (int i = 0; i < 16; i++) s4[t + i * 128] = x4[t + i * 128];
    }
    __syncthreads();
    const int cg = t & 31;
    const int rbase = (t >> 5) * 8;
    float4 acc[8];
    #pragma unroll
    for (int r = 0; r < 8; r++) acc[r] = make_float4(0.f, 0.f, 0.f, 0.f);
    #pragma unroll 4
    for (int k = 0; k < 256; k++) {
        float4 w = W1[k * 32 + cg];
        #pragma unroll
        for (int r = 0; r < 8; r++) {
            float xv = xs[rbase + r][k];
            acc[r].x += xv * w.x; acc[r].y += xv * w.y;
            acc[r].z += xv * w.z; acc[r].w += xv * w.w;
        }
    }
    float4 asw = ((const float4*)att_s)[cg];
    float4 adw = ((const float4*)att_d)[cg];
    const int h = cg >> 2;
    #pragma unroll
    for (int r = 0; r < 8; r++) {
        int row = row0 + rbase + r;
        *(float4*)(h1 + (size_t)row * 128 + 4 * cg) = acc[r];
        float ps = acc[r].x * asw.x + acc[r].y * asw.y + acc[r].z * asw.z + acc[r].w * asw.w;
        float pd = acc[r].x * adw.x + acc[r].y * adw.y + acc[r].z * adw.z + acc[r].w * adw.w;
        ps += __shfl_xor(ps, 1, 64); ps += __shfl_xor(ps, 2, 64);
        pd += __shfl_xor(pd, 1, 64); pd += __shfl_xor(pd, 2, 64);
        if ((cg & 3) == 0) { a1s[row * 8 + h] = ps; a1d[row * 8 + h] = pd; }
    }
}

// ---------------------------------------------------------------------------
// agg1: one wave per dst node. Pure gather+FMA (weights precomputed).
// lane: head = lane>>3, cols 2*lane, 2*lane+1. Fused /denom, +b1, ELU.
// ---------------------------------------------------------------------------
__global__ void __launch_bounds__(256) agg1_kernel(
        const float* __restrict__ h1, const float* __restrict__ ew1,
        const int* __restrict__ rowstart, const int* __restrict__ deg,
        const int* __restrict__ csr_src, const float* __restrict__ b1,
        float* __restrict__ h2in, int n) {
    const int lane = threadIdx.x & 63;
    const int node = blockIdx.x * 4 + (threadIdx.x >> 6);
    if (node >= n) return;
    const int h = lane >> 3;
    const int start = rowstart[node];
    const int d = deg[node];
    float l = 0.f, acc0 = 0.f, acc1 = 0.f;
    int i = 0;
    for (; i + 2 <= d; i += 2) {
        int slot0 = start + i, slot1 = slot0 + 1;
        int s0 = csr_src[slot0], s1 = csr_src[slot1];
        float e0 = ew1[(size_t)slot0 * 8 + h];
        float e1 = ew1[(size_t)slot1 * 8 + h];
        float2 hv0 = *(const float2*)(h1 + (size_t)s0 * 128 + lane * 2);
        float2 hv1 = *(const float2*)(h1 + (size_t)s1 * 128 + lane * 2);
        l += e0 + e1;
        acc0 += e0 * hv0.x + e1 * hv1.x;
        acc1 += e0 * hv0.y + e1 * hv1.y;
    }
    if (i < d) {
        int slot0 = start + i;
        int s0 = csr_src[slot0];
        float e0 = ew1[(size_t)slot0 * 8 + h];
        float2 hv0 = *(const float2*)(h1 + (size_t)s0 * 128 + lane * 2);
        l += e0; acc0 += e0 * hv0.x; acc1 += e0 * hv0.y;
    }
    float inv = 1.f / (l + 1e-16f);
    float v0 = acc0 * inv + b1[lane * 2];
    float v1 = acc1 * inv + b1[lane * 2 + 1];
    v0 = (v0 > 0.f) ? v0 : expm1f(v0);
    v1 = (v1 > 0.f) ? v1 : expm1f(v1);
    *(float2*)(h2in + (size_t)node * 128 + lane * 2) = make_float2(v0, v1);
}

// ---------------------------------------------------------------------------
// GEMM2: t2 = h2in[N,128] @ W2[128,64]; fused a2s/a2d dots.
// ---------------------------------------------------------------------------
__global__ void __launch_bounds__(128) gemm2_kernel(
        const float* __restrict__ h2in, const float4* __restrict__ W2,
        const float* __restrict__ att_s, const float* __restrict__ att_d,
        float* __restrict__ t2, float* __restrict__ a2s, float* __restrict__ a2d, int n) {
    __shared__ float xs[64][128];
    const int t = threadIdx.x;
    const int row0 = blockIdx.x * 64;
    {
        float4* s4 = (float4*)xs;
        #pragma unroll
        for (int i = 0; i < 16; i++) {
            int idx = t + i * 128;
            int row = row0 + (idx >> 5);
            s4[idx] = (row < n) ? ((const float4*)h2in)[(size_t)row * 32 + (idx & 31)]
                                : make_float4(0.f, 0.f, 0.f, 0.f);
        }
    }
    __syncthreads();
    const int cg = t & 15;
    const int rbase = (t >> 4) * 8;
    float4 acc[8];
    #pragma unroll
    for (int r = 0; r < 8; r++) acc[r] = make_float4(0.f, 0.f, 0.f, 0.f);
    #pragma unroll 4
    for (int k = 0; k < 128; k++) {
        float4 w = W2[k * 16 + cg];
        #pragma unroll
        for (int r = 0; r < 8; r++) {
            float xv = xs[rbase + r][k];
            acc[r].x += xv * w.x; acc[r].y += xv * w.y;
            acc[r].z += xv * w.z; acc[r].w += xv * w.w;
        }
    }
    float4 asw = ((const float4*)att_s)[cg];
    float4 adw = ((const float4*)att_d)[cg];
    #pragma unroll
    for (int r = 0; r < 8; r++) {
        int row = row0 + rbase + r;
        if (row >= n) continue;
        *(float4*)(t2 + (size_t)row * 64 + 4 * cg) = acc[r];
        float ps = acc[r].x * asw.x + acc[r].y * asw.y + acc[r].z * asw.z + acc[r].w * asw.w;
        float pd = acc[r].x * adw.x + acc[r].y * adw.y + acc[r].z * adw.z + acc[r].w * adw.w;
        ps += __shfl_xor(ps, 1, 64); ps += __shfl_xor(ps, 2, 64);
        ps += __shfl_xor(ps, 4, 64); ps += __shfl_xor(ps, 8, 64);
        pd += __shfl_xor(pd, 1, 64); pd += __shfl_xor(pd, 2, 64);
        pd += __shfl_xor(pd, 4, 64); pd += __shfl_xor(pd, 8, 64);
        if (cg == 0) { a2s[row] = ps; a2d[row] = pd; }
    }
}

// ---------------------------------------------------------------------------
// Layer-2 edge weights, per CSR slot (streaming; a2s/a2d tables are L2-hot).
// ---------------------------------------------------------------------------
__global__ void w2_kernel(const int* __restrict__ csr_src, const int* __restrict__ csr_dst,
                          const float* __restrict__ a2s, const float* __restrict__ a2d,
                          float* __restrict__ ew2, int E) {
    int i = blockIdx.x * 256 + threadIdx.x;
    if (i >= E) return;
    ew2[i] = expf(lrelu(a2s[csr_src[i]] + a2d[csr_dst[i]]));
}

// ---------------------------------------------------------------------------
// agg2: one wave per dst node, lane = channel. Gather+FMA, fused bias +
// log_softmax across the 64 lanes.
// ---------------------------------------------------------------------------
__global__ void __launch_bounds__(256) agg2_kernel(
        const float* __restrict__ t2, const float* __restrict__ ew2,
        const int* __restrict__ rowstart, const int* __restrict__ deg,
        const int* __restrict__ csr_src, const float* __restrict__ b2,
        float* __restrict__ out, int n) {
    const int lane = threadIdx.x & 63;
    const int node = blockIdx.x * 4 + (threadIdx.x >> 6);
    if (node >= n) return;
    const int start = rowstart[node];
    const int d = deg[node];
    float l = 0.f, acc = 0.f;
    int i = 0;
    for (; i + 2 <= d; i += 2) {
        int slot0 = start + i, slot1 = slot0 + 1;
        int s0 = csr_src[slot0], s1 = csr_src[slot1];
        float e0 = ew2[slot0], e1 = ew2[slot1];
        float hv0 = t2[(size_t)s0 * 64 + lane];
        float hv1 = t2[(size_t)s1 * 64 + lane];
        l += e0 + e1;
        acc += e0 * hv0 + e1 * hv1;
    }
    if (i < d) {
        int slot0 = start + i;
        int s0 = csr_src[slot0];
        float e0 = ew2[slot0];
        float hv0 = t2[(size_t)s0 * 64 + lane];
        l += e0; acc += e0 * hv0;
    }
    float v = acc / (l + 1e-16f) + b2[lane];
    float mx = v;
    #pragma unroll
    for (int off = 32; off >= 1; off >>= 1) mx = fmaxf(mx, __shfl_xor(mx, off, 64));
    float ex = expf(v - mx);
    float s2 = ex;
    #pragma unroll
    for (int off = 32; off >= 1; off >>= 1) s2 += __shfl_xor(s2, off, 64);
    out[(size_t)node * 64 + lane] = v - mx - logf(s2);
}

// ---------------------------------------------------------------------------

extern "C" void kernel_launch(void* const* d_in, const int* in_sizes, int n_in,
                              void* d_out, int out_size, void* d_ws, size_t ws_size,
                              hipStream_t stream) {
    const float* x     = (const float*)d_in[0];
    const int*   ei    = (const int*)d_in[1];
    const float* W1    = (const float*)d_in[2];
    const float* att1s = (const float*)d_in[3];
    const float* att1d = (const float*)d_in[4];
    const float* b1    = (const float*)d_in[5];
    const float* W2    = (const float*)d_in[6];
    const float* att2s = (const float*)d_in[7];
    const float* att2d = (const float*)d_in[8];
    const float* b2    = (const float*)d_in[9];
    float* out = (float*)d_out;

    const int N = N_NODES, E = N_EDGES;

    char* p = (char*)d_ws;
    auto take = [&](size_t bytes) {
        char* r = p;
        p += (bytes + 255) & ~(size_t)255;
        return (void*)r;
    };
    int*   deg      = (int*)take((size_t)N * 4);
    int*   rowstart = (int*)take((size_t)N * 4);
    int*   cursor   = (int*)take((size_t)N * 4);
    int*   counter  = (int*)take(256);
    int*   csr_src  = (int*)take((size_t)E * 4);
    int*   csr_dst  = (int*)take((size_t)E * 4);
    float* ew1      = (float*)take((size_t)E * 8 * 4);
    float* h1       = (float*)take((size_t)N * 128 * 4);  // reused as t2
    float* a1s      = (float*)take((size_t)N * 8 * 4);    // reused as a2s
    float* a1d      = (float*)take((size_t)N * 8 * 4);    // reused as a2d
    float* h2in     = (float*)take((size_t)N * 128 * 4);
    float* ew2      = (float*)csr_dst;  // csr_dst dead after w2_kernel? NO — needed by w2.
    // ew2 must not alias csr_dst (w2 reads csr_dst while writing ew2).
    ew2 = (float*)take((size_t)E * 4);
    float* t2  = h1;
    float* a2s = a1s;
    float* a2d = a1d;

    hipMemsetAsync(deg, 0, (size_t)N * 4, stream);
    hipMemsetAsync(counter, 0, 4, stream);

    count_kernel<<<(E + 255) / 256, 256, 0, stream>>>(ei, deg, E);
    alloc_kernel<<<(N + 255) / 256, 256, 0, stream>>>(deg, rowstart, cursor, counter, N);
    gemm1_kernel<<<N / 32, 128, 0, stream>>>(x, (const float4*)W1, att1s, att1d, h1, a1s, a1d);
    scatter_w1_kernel<<<(E + 255) / 256, 256, 0, stream>>>(ei, cursor, csr_src, csr_dst,
                                                           a1s, a1d, ew1, E);
    agg1_kernel<<<(N + 3) / 4, 256, 0, stream>>>(h1, ew1, rowstart, deg, csr_src, b1, h2in, N);
    gemm2_kernel<<<(N + 63) / 64, 128, 0, stream>>>(h2in, (const float4*)W2, att2s, att2d,
                                                    t2, a2s, a2d, N);
    w2_kernel<<<(E + 255) / 256, 256, 0, stream>>>(csr_src, csr_dst, a2s, a2d, ew2, E);
    agg2_kernel<<<(N + 3) / 4, 256, 0, stream>>>(t2, ew2, rowstart, deg, csr_src, b2, out, N);
}

// Round 3
// 786.427 us; speedup vs baseline: 1.1717x; 1.0284x over previous
//
#include <hip/hip_runtime.h>
#include <math.h>

#define N_NODES 100000
#define N_EDGES 1600000

__device__ __forceinline__ float lrelu(float v) {
    return (v > 0.f) ? v : 0.2f * v;
}

// ---------------------------------------------------------------------------
// CSR build: count degrees, allocate rows (wave-aggregated atomic), scatter
// src ids only (dst is implicit = CSR row). No max-subtraction anywhere:
// logits ~N(0,~3); expf overflows at 88 (~31 sigma) — safe.
// ---------------------------------------------------------------------------

__global__ void count_kernel(const int* __restrict__ ei, int* __restrict__ deg, int E) {
    int e = blockIdx.x * 256 + threadIdx.x;
    if (e < E) atomicAdd(&deg[ei[E + e]], 1);
}

__global__ void alloc_kernel(const int* __restrict__ deg, int* __restrict__ rowstart,
                             int* __restrict__ cursor, int* __restrict__ counter, int n) {
    int i = blockIdx.x * 256 + threadIdx.x;
    int lane = threadIdx.x & 63;
    int d = (i < n) ? deg[i] : 0;
    int pre = d;
    #pragma unroll
    for (int off = 1; off < 64; off <<= 1) {
        int v = __shfl_up(pre, off, 64);
        if (lane >= off) pre += v;
    }
    int total = __shfl(pre, 63, 64);
    int base = 0;
    if (lane == 63) base = atomicAdd(counter, total);
    base = __shfl(base, 63, 64);
    int start = base + pre - d;
    if (i < n) { rowstart[i] = start; cursor[i] = start; }
}

__global__ void scatter_kernel(const int* __restrict__ ei, int* __restrict__ cursor,
                               int* __restrict__ csr_src, int E) {
    int e = blockIdx.x * 256 + threadIdx.x;
    if (e < E) {
        int s = ei[e];
        int slot = atomicAdd(&cursor[ei[E + e]], 1);
        csr_src[slot] = s;
    }
}

// ---------------------------------------------------------------------------
// GEMM1: h1 = x[N,256] @ W1[256,128]; fused a1s/a1d attention dots.
// ---------------------------------------------------------------------------
__global__ void __launch_bounds__(128) gemm1_kernel(
        const float* __restrict__ x, const float4* __restrict__ W1,
        const float* __restrict__ att_s, const float* __restrict__ att_d,
        float* __restrict__ h1, float* __restrict__ a1s, float* __restrict__ a1d) {
    __shared__ float xs[32][256];
    const int t = threadIdx.x;
    const int row0 = blockIdx.x * 32;   // 100000 % 32 == 0
    {
        const float4* x4 = (const float4*)(x + (size_t)row0 * 256);
        float4* s4 = (float4*)xs;
        #pragma unroll
        for (int i = 0; i < 16; i++) s4[t + i * 128] = x4[t + i * 128];
    }
    __syncthreads();
    const int cg = t & 31;
    const int rbase = (t >> 5) * 8;
    float4 acc[8];
    #pragma unroll
    for (int r = 0; r < 8; r++) acc[r] = make_float4(0.f, 0.f, 0.f, 0.f);
    #pragma unroll 4
    for (int k = 0; k < 256; k++) {
        float4 w = W1[k * 32 + cg];
        #pragma unroll
        for (int r = 0; r < 8; r++) {
            float xv = xs[rbase + r][k];
            acc[r].x += xv * w.x; acc[r].y += xv * w.y;
            acc[r].z += xv * w.z; acc[r].w += xv * w.w;
        }
    }
    float4 asw = ((const float4*)att_s)[cg];
    float4 adw = ((const float4*)att_d)[cg];
    const int h = cg >> 2;
    #pragma unroll
    for (int r = 0; r < 8; r++) {
        int row = row0 + rbase + r;
        *(float4*)(h1 + (size_t)row * 128 + 4 * cg) = acc[r];
        float ps = acc[r].x * asw.x + acc[r].y * asw.y + acc[r].z * asw.z + acc[r].w * asw.w;
        float pd = acc[r].x * adw.x + acc[r].y * adw.y + acc[r].z * adw.z + acc[r].w * adw.w;
        ps += __shfl_xor(ps, 1, 64); ps += __shfl_xor(ps, 2, 64);
        pd += __shfl_xor(pd, 1, 64); pd += __shfl_xor(pd, 2, 64);
        if ((cg & 3) == 0) { a1s[row * 8 + h] = ps; a1d[row * 8 + h] = pd; }
    }
}

// ---------------------------------------------------------------------------
// agg1: one wave per dst node. Edge weight computed inline (1 indep expf per
// lane-edge; no serial rescale chain). lane: head = lane>>3, cols 2*lane..+1.
// Fused /denom, +b1, ELU. Writes h2in[N,128].
// ---------------------------------------------------------------------------
__global__ void __launch_bounds__(256) agg1_kernel(
        const float* __restrict__ h1, const float* __restrict__ a1s,
        const float* __restrict__ a1d, const int* __restrict__ rowstart,
        const int* __restrict__ deg, const int* __restrict__ csr_src,
        const float* __restrict__ b1, float* __restrict__ h2in, int n) {
    const int lane = threadIdx.x & 63;
    const int node = blockIdx.x * 4 + (threadIdx.x >> 6);
    if (node >= n) return;
    const int h = lane >> 3;
    const int start = rowstart[node];
    const int d = deg[node];
    const float ad = a1d[node * 8 + h];
    float l = 0.f, acc0 = 0.f, acc1 = 0.f;
    int i = 0;
    for (; i + 2 <= d; i += 2) {
        int s0 = csr_src[start + i];
        int s1 = csr_src[start + i + 1];
        float as0 = a1s[s0 * 8 + h];
        float as1 = a1s[s1 * 8 + h];
        float2 hv0 = *(const float2*)(h1 + (size_t)s0 * 128 + lane * 2);
        float2 hv1 = *(const float2*)(h1 + (size_t)s1 * 128 + lane * 2);
        float e0 = __expf(lrelu(as0 + ad));
        float e1 = __expf(lrelu(as1 + ad));
        l += e0 + e1;
        acc0 += e0 * hv0.x + e1 * hv1.x;
        acc1 += e0 * hv0.y + e1 * hv1.y;
    }
    if (i < d) {
        int s0 = csr_src[start + i];
        float as0 = a1s[s0 * 8 + h];
        float2 hv0 = *(const float2*)(h1 + (size_t)s0 * 128 + lane * 2);
        float e0 = __expf(lrelu(as0 + ad));
        l += e0; acc0 += e0 * hv0.x; acc1 += e0 * hv0.y;
    }
    float inv = 1.f / (l + 1e-16f);
    float v0 = acc0 * inv + b1[lane * 2];
    float v1 = acc1 * inv + b1[lane * 2 + 1];
    v0 = (v0 > 0.f) ? v0 : expm1f(v0);
    v1 = (v1 > 0.f) ? v1 : expm1f(v1);
    *(float2*)(h2in + (size_t)node * 128 + lane * 2) = make_float2(v0, v1);
}

// ---------------------------------------------------------------------------
// GEMM2: t2 = h2in[N,128] @ W2[128,64]; fused a2s/a2d dots.
// ---------------------------------------------------------------------------
__global__ void __launch_bounds__(128) gemm2_kernel(
        const float* __restrict__ h2in, const float4* __restrict__ W2,
        const float* __restrict__ att_s, const float* __restrict__ att_d,
        float* __restrict__ t2, float* __restrict__ a2s, float* __restrict__ a2d, int n) {
    __shared__ float xs[64][128];
    const int t = threadIdx.x;
    const int row0 = blockIdx.x * 64;
    {
        float4* s4 = (float4*)xs;
        #pragma unroll
        for (int i = 0; i < 16; i++) {
            int idx = t + i * 128;
            int row = row0 + (idx >> 5);
            s4[idx] = (row < n) ? ((const float4*)h2in)[(size_t)row * 32 + (idx & 31)]
                                : make_float4(0.f, 0.f, 0.f, 0.f);
        }
    }
    __syncthreads();
    const int cg = t & 15;
    const int rbase = (t >> 4) * 8;
    float4 acc[8];
    #pragma unroll
    for (int r = 0; r < 8; r++) acc[r] = make_float4(0.f, 0.f, 0.f, 0.f);
    #pragma unroll 4
    for (int k = 0; k < 128; k++) {
        float4 w = W2[k * 16 + cg];
        #pragma unroll
        for (int r = 0; r < 8; r++) {
            float xv = xs[rbase + r][k];
            acc[r].x += xv * w.x; acc[r].y += xv * w.y;
            acc[r].z += xv * w.z; acc[r].w += xv * w.w;
        }
    }
    float4 asw = ((const float4*)att_s)[cg];
    float4 adw = ((const float4*)att_d)[cg];
    #pragma unroll
    for (int r = 0; r < 8; r++) {
        int row = row0 + rbase + r;
        if (row >= n) continue;
        *(float4*)(t2 + (size_t)row * 64 + 4 * cg) = acc[r];
        float ps = acc[r].x * asw.x + acc[r].y * asw.y + acc[r].z * asw.z + acc[r].w * asw.w;
        float pd = acc[r].x * adw.x + acc[r].y * adw.y + acc[r].z * adw.z + acc[r].w * adw.w;
        ps += __shfl_xor(ps, 1, 64); ps += __shfl_xor(ps, 2, 64);
        ps += __shfl_xor(ps, 4, 64); ps += __shfl_xor(ps, 8, 64);
        pd += __shfl_xor(pd, 1, 64); pd += __shfl_xor(pd, 2, 64);
        pd += __shfl_xor(pd, 4, 64); pd += __shfl_xor(pd, 8, 64);
        if (cg == 0) { a2s[row] = ps; a2d[row] = pd; }
    }
}

// ---------------------------------------------------------------------------
// agg2: one wave per dst node, lane = channel. Inline edge weight, fused
// bias + log_softmax across the 64 lanes. Writes final output.
// ---------------------------------------------------------------------------
__global__ void __launch_bounds__(256) agg2_kernel(
        const float* __restrict__ t2, const float* __restrict__ a2s,
        const float* __restrict__ a2d, const int* __restrict__ rowstart,
        const int* __restrict__ deg, const int* __restrict__ csr_src,
        const float* __restrict__ b2, float* __restrict__ out, int n) {
    const int lane = threadIdx.x & 63;
    const int node = blockIdx.x * 4 + (threadIdx.x >> 6);
    if (node >= n) return;
    const int start = rowstart[node];
    const int d = deg[node];
    const float ad = a2d[node];
    float l = 0.f, acc = 0.f;
    int i = 0;
    for (; i + 2 <= d; i += 2) {
        int s0 = csr_src[start + i];
        int s1 = csr_src[start + i + 1];
        float as0 = a2s[s0];
        float as1 = a2s[s1];
        float hv0 = t2[(size_t)s0 * 64 + lane];
        float hv1 = t2[(size_t)s1 * 64 + lane];
        float e0 = __expf(lrelu(as0 + ad));
        float e1 = __expf(lrelu(as1 + ad));
        l += e0 + e1;
        acc += e0 * hv0 + e1 * hv1;
    }
    if (i < d) {
        int s0 = csr_src[start + i];
        float as0 = a2s[s0];
        float hv0 = t2[(size_t)s0 * 64 + lane];
        float e0 = __expf(lrelu(as0 + ad));
        l += e0; acc += e0 * hv0;
    }
    float v = acc / (l + 1e-16f) + b2[lane];
    float mx = v;
    #pragma unroll
    for (int off = 32; off >= 1; off >>= 1) mx = fmaxf(mx, __shfl_xor(mx, off, 64));
    float ex = expf(v - mx);
    float s2 = ex;
    #pragma unroll
    for (int off = 32; off >= 1; off >>= 1) s2 += __shfl_xor(s2, off, 64);
    out[(size_t)node * 64 + lane] = v - mx - logf(s2);
}

// ---------------------------------------------------------------------------

extern "C" void kernel_launch(void* const* d_in, const int* in_sizes, int n_in,
                              void* d_out, int out_size, void* d_ws, size_t ws_size,
                              hipStream_t stream) {
    const float* x     = (const float*)d_in[0];
    const int*   ei    = (const int*)d_in[1];
    const float* W1    = (const float*)d_in[2];
    const float* att1s = (const float*)d_in[3];
    const float* att1d = (const float*)d_in[4];
    const float* b1    = (const float*)d_in[5];
    const float* W2    = (const float*)d_in[6];
    const float* att2s = (const float*)d_in[7];
    const float* att2d = (const float*)d_in[8];
    const float* b2    = (const float*)d_in[9];
    float* out = (float*)d_out;

    const int N = N_NODES, E = N_EDGES;

    char* p = (char*)d_ws;
    auto take = [&](size_t bytes) {
        char* r = p;
        p += (bytes + 255) & ~(size_t)255;
        return (void*)r;
    };
    int*   deg      = (int*)take((size_t)N * 4);
    int*   rowstart = (int*)take((size_t)N * 4);
    int*   cursor   = (int*)take((size_t)N * 4);
    int*   counter  = (int*)take(256);
    int*   csr_src  = (int*)take((size_t)E * 4);
    float* h1       = (float*)take((size_t)N * 128 * 4);  // reused as t2
    float* a1s      = (float*)take((size_t)N * 8 * 4);    // reused as a2s
    float* a1d      = (float*)take((size_t)N * 8 * 4);    // reused as a2d
    float* h2in     = (float*)take((size_t)N * 128 * 4);
    float* t2  = h1;
    float* a2s = a1s;
    float* a2d = a1d;

    hipMemsetAsync(deg, 0, (size_t)N * 4, stream);
    hipMemsetAsync(counter, 0, 4, stream);

    count_kernel<<<(E + 255) / 256, 256, 0, stream>>>(ei, deg, E);
    alloc_kernel<<<(N + 255) / 256, 256, 0, stream>>>(deg, rowstart, cursor, counter, N);
    scatter_kernel<<<(E + 255) / 256, 256, 0, stream>>>(ei, cursor, csr_src, E);
    gemm1_kernel<<<N / 32, 128, 0, stream>>>(x, (const float4*)W1, att1s, att1d, h1, a1s, a1d);
    agg1_kernel<<<(N + 3) / 4, 256, 0, stream>>>(h1, a1s, a1d, rowstart, deg, csr_src, b1, h2in, N);
    gemm2_kernel<<<(N + 63) / 64, 128, 0, stream>>>(h2in, (const float4*)W2, att2s, att2d,
                                                    t2, a2s, a2d, N);
    agg2_kernel<<<(N + 3) / 4, 256, 0, stream>>>(t2, a2s, a2d, rowstart, deg, csr_src, b2, out, N);
}

// Round 4
// 690.658 us; speedup vs baseline: 1.3342x; 1.1387x over previous
//
#include <hip/hip_runtime.h>
#include <math.h>

#define N_NODES 100000
#define N_EDGES 1600000

typedef __attribute__((ext_vector_type(8))) short short8;    // 8 x bf16 bits
typedef __attribute__((ext_vector_type(4))) float floatx4;   // MFMA acc

__device__ __forceinline__ float lrelu(float v) {
    return (v > 0.f) ? v : 0.2f * v;
}

__device__ __forceinline__ unsigned short f2bf(float f) {
    unsigned int u = __float_as_uint(f);
    u += 0x7fff + ((u >> 16) & 1);   // round-to-nearest-even
    return (unsigned short)(u >> 16);
}

// ---------------------------------------------------------------------------
// CSR build: count degrees, allocate rows (wave-aggregated atomic), scatter
// src ids only. No max-subtraction anywhere: logits ~N(0,~3); expf overflows
// at 88 (~31 sigma) — safe.
// ---------------------------------------------------------------------------

__global__ void count_kernel(const int* __restrict__ ei, int* __restrict__ deg, int E) {
    int e = blockIdx.x * 256 + threadIdx.x;
    if (e < E) atomicAdd(&deg[ei[E + e]], 1);
}

__global__ void alloc_kernel(const int* __restrict__ deg, int* __restrict__ rowstart,
                             int* __restrict__ cursor, int* __restrict__ counter, int n) {
    int i = blockIdx.x * 256 + threadIdx.x;
    int lane = threadIdx.x & 63;
    int d = (i < n) ? deg[i] : 0;
    int pre = d;
    #pragma unroll
    for (int off = 1; off < 64; off <<= 1) {
        int v = __shfl_up(pre, off, 64);
        if (lane >= off) pre += v;
    }
    int total = __shfl(pre, 63, 64);
    int base = 0;
    if (lane == 63) base = atomicAdd(counter, total);
    base = __shfl(base, 63, 64);
    int start = base + pre - d;
    if (i < n) { rowstart[i] = start; cursor[i] = start; }
}

__global__ void scatter_kernel(const int* __restrict__ ei, int* __restrict__ cursor,
                               int* __restrict__ csr_src, int E) {
    int e = blockIdx.x * 256 + threadIdx.x;
    if (e < E) {
        int s = ei[e];
        int slot = atomicAdd(&cursor[ei[E + e]], 1);
        csr_src[slot] = s;
    }
}

// ---------------------------------------------------------------------------
// W1 pre-swizzle: fp32 [256,128] -> bf16 B-fragment order.
// Frag idx = (t*8+ks)*64 + lane ; lane holds B[k=ks*32+quad*8+j][n=t*16+l15],
// j=0..7, packed 16B. 4096 threads total; output 64 KB, stays L2-hot.
// ---------------------------------------------------------------------------
__global__ void w1swz_kernel(const float* __restrict__ W1, unsigned short* __restrict__ w1b) {
    int idx = blockIdx.x * 256 + threadIdx.x;   // 0..4095
    int lane = idx & 63;
    int ts = idx >> 6;            // t*8 + ks
    int t = ts >> 3, ks = ts & 7;
    int quad = lane >> 4, l15 = lane & 15;
    int kbase = ks * 32 + quad * 8;
    unsigned short o[8];
    #pragma unroll
    for (int j = 0; j < 8; j++)
        o[j] = f2bf(W1[(size_t)(kbase + j) * 128 + t * 16 + l15]);
    uint4 pk;
    pk.x = o[0] | ((unsigned int)o[1] << 16);
    pk.y = o[2] | ((unsigned int)o[3] << 16);
    pk.z = o[4] | ((unsigned int)o[5] << 16);
    pk.w = o[6] | ((unsigned int)o[7] << 16);
    ((uint4*)w1b)[idx] = pk;
}

// ---------------------------------------------------------------------------
// GEMM1 (MFMA bf16): h1b = bf16(x[N,256] @ W1[256,128]); fused a1s/a1d dots
// computed in fp32 from the accumulators. 4 waves/block, wave = 16 rows x 128
// cols (8 tiles of 16x16, A-frag reused 8x). No LDS.
// ---------------------------------------------------------------------------
__global__ void __launch_bounds__(256) gemm1_kernel(
        const float* __restrict__ x, const short8* __restrict__ w1b,
        const float* __restrict__ att_s, const float* __restrict__ att_d,
        unsigned short* __restrict__ h1b, float* __restrict__ a1s, float* __restrict__ a1d) {
    const int lane = threadIdx.x & 63;
    const int wv = threadIdx.x >> 6;
    const int quad = lane >> 4;
    const int l15 = lane & 15;
    const int M = N_NODES;

    const int rowA = blockIdx.x * 64 + wv * 16 + l15;   // row this lane feeds into A
    const bool rowAok = rowA < M;
    const float4* xrow4 = (const float4*)(x + (size_t)rowA * 256);

    floatx4 acc[8];
    #pragma unroll
    for (int t = 0; t < 8; t++) acc[t] = (floatx4){0.f, 0.f, 0.f, 0.f};

    #pragma unroll
    for (int ks = 0; ks < 8; ks++) {
        float4 p0, p1;
        if (rowAok) {
            p0 = xrow4[ks * 8 + quad * 2];
            p1 = xrow4[ks * 8 + quad * 2 + 1];
        } else {
            p0 = make_float4(0.f, 0.f, 0.f, 0.f);
            p1 = p0;
        }
        short8 af;
        af[0] = (short)f2bf(p0.x); af[1] = (short)f2bf(p0.y);
        af[2] = (short)f2bf(p0.z); af[3] = (short)f2bf(p0.w);
        af[4] = (short)f2bf(p1.x); af[5] = (short)f2bf(p1.y);
        af[6] = (short)f2bf(p1.z); af[7] = (short)f2bf(p1.w);
        #pragma unroll
        for (int t = 0; t < 8; t++) {
            short8 bf = w1b[(t * 8 + ks) * 64 + lane];
            acc[t] = __builtin_amdgcn_mfma_f32_16x16x32_bf16(af, bf, acc[t], 0, 0, 0);
        }
    }

    // Epilogue: C layout col = l15, row = quad*4 + r  (tile t == head t).
    const int rowC0 = blockIdx.x * 64 + wv * 16 + quad * 4;
    #pragma unroll
    for (int t = 0; t < 8; t++) {
        float asw = att_s[t * 16 + l15];
        float adw = att_d[t * 16 + l15];
        #pragma unroll
        for (int r = 0; r < 4; r++) {
            int grow = rowC0 + r;
            float c = acc[t][r];
            if (grow < M) h1b[(size_t)grow * 128 + t * 16 + l15] = f2bf(c);
            float ps = c * asw;
            float pd = c * adw;
            ps += __shfl_xor(ps, 1, 64); ps += __shfl_xor(ps, 2, 64);
            ps += __shfl_xor(ps, 4, 64); ps += __shfl_xor(ps, 8, 64);
            pd += __shfl_xor(pd, 1, 64); pd += __shfl_xor(pd, 2, 64);
            pd += __shfl_xor(pd, 4, 64); pd += __shfl_xor(pd, 8, 64);
            if (l15 == 0 && grow < M) { a1s[grow * 8 + t] = ps; a1d[grow * 8 + t] = pd; }
        }
    }
}

// ---------------------------------------------------------------------------
// agg1: one wave per dst node. Edge weight inline; h1 gathered as bf16
// (one uint = 2 cols per lane). Fused /denom, +b1, ELU. Writes h2in fp32.
// ---------------------------------------------------------------------------
__global__ void __launch_bounds__(256) agg1_kernel(
        const unsigned short* __restrict__ h1b, const float* __restrict__ a1s,
        const float* __restrict__ a1d, const int* __restrict__ rowstart,
        const int* __restrict__ deg, const int* __restrict__ csr_src,
        const float* __restrict__ b1, float* __restrict__ h2in, int n) {
    const int lane = threadIdx.x & 63;
    const int node = blockIdx.x * 4 + (threadIdx.x >> 6);
    if (node >= n) return;
    const int h = lane >> 3;
    const int start = rowstart[node];
    const int d = deg[node];
    const float ad = a1d[node * 8 + h];
    float l = 0.f, acc0 = 0.f, acc1 = 0.f;
    int i = 0;
    for (; i + 2 <= d; i += 2) {
        int s0 = csr_src[start + i];
        int s1 = csr_src[start + i + 1];
        float as0 = a1s[s0 * 8 + h];
        float as1 = a1s[s1 * 8 + h];
        unsigned int u0 = *(const unsigned int*)(h1b + (size_t)s0 * 128 + lane * 2);
        unsigned int u1 = *(const unsigned int*)(h1b + (size_t)s1 * 128 + lane * 2);
        float e0 = __expf(lrelu(as0 + ad));
        float e1 = __expf(lrelu(as1 + ad));
        float h0x = __uint_as_float(u0 << 16);
        float h0y = __uint_as_float(u0 & 0xffff0000u);
        float h1x = __uint_as_float(u1 << 16);
        float h1y = __uint_as_float(u1 & 0xffff0000u);
        l += e0 + e1;
        acc0 += e0 * h0x + e1 * h1x;
        acc1 += e0 * h0y + e1 * h1y;
    }
    if (i < d) {
        int s0 = csr_src[start + i];
        float as0 = a1s[s0 * 8 + h];
        unsigned int u0 = *(const unsigned int*)(h1b + (size_t)s0 * 128 + lane * 2);
        float e0 = __expf(lrelu(as0 + ad));
        l += e0;
        acc0 += e0 * __uint_as_float(u0 << 16);
        acc1 += e0 * __uint_as_float(u0 & 0xffff0000u);
    }
    float inv = 1.f / (l + 1e-16f);
    float v0 = acc0 * inv + b1[lane * 2];
    float v1 = acc1 * inv + b1[lane * 2 + 1];
    v0 = (v0 > 0.f) ? v0 : expm1f(v0);
    v1 = (v1 > 0.f) ? v1 : expm1f(v1);
    *(float2*)(h2in + (size_t)node * 128 + lane * 2) = make_float2(v0, v1);
}

// ---------------------------------------------------------------------------
// GEMM2: t2 = h2in[N,128] @ W2[128,64]; fused a2s/a2d dots. (fp32 vector)
// ---------------------------------------------------------------------------
__global__ void __launch_bounds__(128) gemm2_kernel(
        const float* __restrict__ h2in, const float4* __restrict__ W2,
        const float* __restrict__ att_s, const float* __restrict__ att_d,
        float* __restrict__ t2, float* __restrict__ a2s, float* __restrict__ a2d, int n) {
    __shared__ float xs[64][128];
    const int t = threadIdx.x;
    const int row0 = blockIdx.x * 64;
    {
        float4* s4 = (float4*)xs;
        #pragma unroll
        for (int i = 0; i < 16; i++) {
            int idx = t + i * 128;
            int row = row0 + (idx >> 5);
            s4[idx] = (row < n) ? ((const float4*)h2in)[(size_t)row * 32 + (idx & 31)]
                                : make_float4(0.f, 0.f, 0.f, 0.f);
        }
    }
    __syncthreads();
    const int cg = t & 15;
    const int rbase = (t >> 4) * 8;
    float4 acc[8];
    #pragma unroll
    for (int r = 0; r < 8; r++) acc[r] = make_float4(0.f, 0.f, 0.f, 0.f);
    #pragma unroll 4
    for (int k = 0; k < 128; k++) {
        float4 w = W2[k * 16 + cg];
        #pragma unroll
        for (int r = 0; r < 8; r++) {
            float xv = xs[rbase + r][k];
            acc[r].x += xv * w.x; acc[r].y += xv * w.y;
            acc[r].z += xv * w.z; acc[r].w += xv * w.w;
        }
    }
    float4 asw = ((const float4*)att_s)[cg];
    float4 adw = ((const float4*)att_d)[cg];
    #pragma unroll
    for (int r = 0; r < 8; r++) {
        int row = row0 + rbase + r;
        if (row >= n) continue;
        *(float4*)(t2 + (size_t)row * 64 + 4 * cg) = acc[r];
        float ps = acc[r].x * asw.x + acc[r].y * asw.y + acc[r].z * asw.z + acc[r].w * asw.w;
        float pd = acc[r].x * adw.x + acc[r].y * adw.y + acc[r].z * adw.z + acc[r].w * adw.w;
        ps += __shfl_xor(ps, 1, 64); ps += __shfl_xor(ps, 2, 64);
        ps += __shfl_xor(ps, 4, 64); ps += __shfl_xor(ps, 8, 64);
        pd += __shfl_xor(pd, 1, 64); pd += __shfl_xor(pd, 2, 64);
        pd += __shfl_xor(pd, 4, 64); pd += __shfl_xor(pd, 8, 64);
        if (cg == 0) { a2s[row] = ps; a2d[row] = pd; }
    }
}

// ---------------------------------------------------------------------------
// agg2: one wave per dst node, lane = channel. Inline edge weight, fused
// bias + log_softmax across the 64 lanes. Writes final output.
// ---------------------------------------------------------------------------
__global__ void __launch_bounds__(256) agg2_kernel(
        const float* __restrict__ t2, const float* __restrict__ a2s,
        const float* __restrict__ a2d, const int* __restrict__ rowstart,
        const int* __restrict__ deg, const int* __restrict__ csr_src,
        const float* __restrict__ b2, float* __restrict__ out, int n) {
    const int lane = threadIdx.x & 63;
    const int node = blockIdx.x * 4 + (threadIdx.x >> 6);
    if (node >= n) return;
    const int start = rowstart[node];
    const int d = deg[node];
    const float ad = a2d[node];
    float l = 0.f, acc = 0.f;
    int i = 0;
    for (; i + 2 <= d; i += 2) {
        int s0 = csr_src[start + i];
        int s1 = csr_src[start + i + 1];
        float as0 = a2s[s0];
        float as1 = a2s[s1];
        float hv0 = t2[(size_t)s0 * 64 + lane];
        float hv1 = t2[(size_t)s1 * 64 + lane];
        float e0 = __expf(lrelu(as0 + ad));
        float e1 = __expf(lrelu(as1 + ad));
        l += e0 + e1;
        acc += e0 * hv0 + e1 * hv1;
    }
    if (i < d) {
        int s0 = csr_src[start + i];
        float as0 = a2s[s0];
        float hv0 = t2[(size_t)s0 * 64 + lane];
        float e0 = __expf(lrelu(as0 + ad));
        l += e0; acc += e0 * hv0;
    }
    float v = acc / (l + 1e-16f) + b2[lane];
    float mx = v;
    #pragma unroll
    for (int off = 32; off >= 1; off >>= 1) mx = fmaxf(mx, __shfl_xor(mx, off, 64));
    float ex = expf(v - mx);
    float s2 = ex;
    #pragma unroll
    for (int off = 32; off >= 1; off >>= 1) s2 += __shfl_xor(s2, off, 64);
    out[(size_t)node * 64 + lane] = v - mx - logf(s2);
}

// ---------------------------------------------------------------------------

extern "C" void kernel_launch(void* const* d_in, const int* in_sizes, int n_in,
                              void* d_out, int out_size, void* d_ws, size_t ws_size,
                              hipStream_t stream) {
    const float* x     = (const float*)d_in[0];
    const int*   ei    = (const int*)d_in[1];
    const float* W1    = (const float*)d_in[2];
    const float* att1s = (const float*)d_in[3];
    const float* att1d = (const float*)d_in[4];
    const float* b1    = (const float*)d_in[5];
    const float* W2    = (const float*)d_in[6];
    const float* att2s = (const float*)d_in[7];
    const float* att2d = (const float*)d_in[8];
    const float* b2    = (const float*)d_in[9];
    float* out = (float*)d_out;

    const int N = N_NODES, E = N_EDGES;

    char* p = (char*)d_ws;
    auto take = [&](size_t bytes) {
        char* r = p;
        p += (bytes + 255) & ~(size_t)255;
        return (void*)r;
    };
    int*            deg      = (int*)take((size_t)N * 4);
    int*            rowstart = (int*)take((size_t)N * 4);
    int*            cursor   = (int*)take((size_t)N * 4);
    int*            counter  = (int*)take(256);
    int*            csr_src  = (int*)take((size_t)E * 4);
    unsigned short* w1b      = (unsigned short*)take(8 * 8 * 64 * 16);        // 64 KB
    unsigned short* h1b      = (unsigned short*)take((size_t)N * 128 * 2);    // bf16
    float*          a1s      = (float*)take((size_t)N * 8 * 4);               // reused a2s
    float*          a1d      = (float*)take((size_t)N * 8 * 4);               // reused a2d
    float*          h2in     = (float*)take((size_t)N * 128 * 4);
    float*          t2       = (float*)take((size_t)N * 64 * 4);
    float* a2s = a1s;
    float* a2d = a1d;

    hipMemsetAsync(deg, 0, (size_t)N * 4, stream);
    hipMemsetAsync(counter, 0, 4, stream);

    count_kernel<<<(E + 255) / 256, 256, 0, stream>>>(ei, deg, E);
    alloc_kernel<<<(N + 255) / 256, 256, 0, stream>>>(deg, rowstart, cursor, counter, N);
    scatter_kernel<<<(E + 255) / 256, 256, 0, stream>>>(ei, cursor, csr_src, E);
    w1swz_kernel<<<16, 256, 0, stream>>>(W1, w1b);
    gemm1_kernel<<<(N + 63) / 64, 256, 0, stream>>>(x, (const short8*)w1b, att1s, att1d,
                                                    h1b, a1s, a1d);
    agg1_kernel<<<(N + 3) / 4, 256, 0, stream>>>(h1b, a1s, a1d, rowstart, deg, csr_src,
                                                 b1, h2in, N);
    gemm2_kernel<<<(N + 63) / 64, 128, 0, stream>>>(h2in, (const float4*)W2, att2s, att2d,
                                                    t2, a2s, a2d, N);
    agg2_kernel<<<(N + 3) / 4, 256, 0, stream>>>(t2, a2s, a2d, rowstart, deg, csr_src,
                                                 b2, out, N);
}

// Round 5
// 633.234 us; speedup vs baseline: 1.4552x; 1.0907x over previous
//
#include <hip/hip_runtime.h>
#include <math.h>

#define N_NODES 100000
#define N_EDGES 1600000
#define GEMM1_BLOCKS ((N_NODES + 63) / 64)    // 1563
#define LINK_BLOCKS  ((N_EDGES + 255) / 256)  // 6250

typedef __attribute__((ext_vector_type(8))) short short8;    // 8 x bf16 bits
typedef __attribute__((ext_vector_type(4))) float floatx4;   // MFMA acc

__device__ __forceinline__ float lrelu(float v) {
    return (v > 0.f) ? v : 0.2f * v;
}

__device__ __forceinline__ unsigned short f2bf(float f) {
    unsigned int u = __float_as_uint(f);
    u += 0x7fff + ((u >> 16) & 1);   // round-to-nearest-even
    return (unsigned short)(u >> 16);
}

__device__ __forceinline__ float bflo(unsigned int u) { return __uint_as_float(u << 16); }
__device__ __forceinline__ float bfhi(unsigned int u) { return __uint_as_float(u & 0xffff0000u); }

// ---------------------------------------------------------------------------
// prep: swizzle W1 (fp32 [256,128]) and W2 (fp32 [128,64]) into bf16 MFMA
// B-fragment order. w1b: frag (t*8+ks)*64+lane, t=0..7 (16-col tile),
// ks=0..7 (K/32). w2b: frag (t*4+ks)*64+lane, t=0..3, ks=0..3.
// lane holds B[k=ks*32+quad*8+j][n=t*16+l15], j=0..7, packed 16B.
// ---------------------------------------------------------------------------
__global__ void prep_kernel(const float* __restrict__ W1, const float* __restrict__ W2,
                            unsigned short* __restrict__ w1b, unsigned short* __restrict__ w2b) {
    int idx = blockIdx.x * 256 + threadIdx.x;
    if (idx < 4096) {
        int lane = idx & 63;
        int ts = idx >> 6;
        int t = ts >> 3, ks = ts & 7;
        int quad = lane >> 4, l15 = lane & 15;
        int kbase = ks * 32 + quad * 8;
        unsigned short o[8];
        #pragma unroll
        for (int j = 0; j < 8; j++)
            o[j] = f2bf(W1[(size_t)(kbase + j) * 128 + t * 16 + l15]);
        uint4 pk;
        pk.x = o[0] | ((unsigned int)o[1] << 16);
        pk.y = o[2] | ((unsigned int)o[3] << 16);
        pk.z = o[4] | ((unsigned int)o[5] << 16);
        pk.w = o[6] | ((unsigned int)o[7] << 16);
        ((uint4*)w1b)[idx] = pk;
    } else if (idx < 4096 + 1024) {
        int idx2 = idx - 4096;
        int lane = idx2 & 63;
        int ts = idx2 >> 6;
        int t = ts >> 2, ks = ts & 3;
        int quad = lane >> 4, l15 = lane & 15;
        int kbase = ks * 32 + quad * 8;
        unsigned short o[8];
        #pragma unroll
        for (int j = 0; j < 8; j++)
            o[j] = f2bf(W2[(size_t)(kbase + j) * 64 + t * 16 + l15]);
        uint4 pk;
        pk.x = o[0] | ((unsigned int)o[1] << 16);
        pk.y = o[2] | ((unsigned int)o[3] << 16);
        pk.z = o[4] | ((unsigned int)o[5] << 16);
        pk.w = o[6] | ((unsigned int)o[7] << 16);
        ((uint4*)w2b)[idx2] = pk;
    }
}

// ---------------------------------------------------------------------------
// Fused GEMM1 (MFMA bf16) + edge linked-list build.
// Blocks [0, GEMM1_BLOCKS): h1b = bf16(x @ W1), fused a1s/a1d head dots.
//   4 waves/block, wave = 16 rows x 128 cols (8 16x16 tiles), no LDS.
// Blocks [GEMM1_BLOCKS, +LINK_BLOCKS): nxt[e] = atomicExch(&head[dst], e).
//   Coalesced nxt write (vs 16x-amplified random CSR scatter); head is
//   400 KB, LLC-resident. head pre-memset to -1.
// ---------------------------------------------------------------------------
__global__ void __launch_bounds__(256) gemm1_link_kernel(
        const float* __restrict__ x, const short8* __restrict__ w1b,
        const float* __restrict__ att_s, const float* __restrict__ att_d,
        unsigned short* __restrict__ h1b, float* __restrict__ a1s, float* __restrict__ a1d,
        const int* __restrict__ ei, int* __restrict__ head, int* __restrict__ nxt) {
    const int bid = blockIdx.x;
    if (bid >= GEMM1_BLOCKS) {
        int e = (bid - GEMM1_BLOCKS) * 256 + threadIdx.x;
        if (e < N_EDGES) {
            int d = ei[N_EDGES + e];
            nxt[e] = atomicExch(&head[d], e);
        }
        return;
    }
    const int lane = threadIdx.x & 63;
    const int wv = threadIdx.x >> 6;
    const int quad = lane >> 4;
    const int l15 = lane & 15;
    const int M = N_NODES;

    const int rowA = bid * 64 + wv * 16 + l15;
    const bool rowAok = rowA < M;
    const float4* xrow4 = (const float4*)(x + (size_t)rowA * 256);

    floatx4 acc[8];
    #pragma unroll
    for (int t = 0; t < 8; t++) acc[t] = (floatx4){0.f, 0.f, 0.f, 0.f};

    #pragma unroll
    for (int ks = 0; ks < 8; ks++) {
        float4 p0, p1;
        if (rowAok) {
            p0 = xrow4[ks * 8 + quad * 2];
            p1 = xrow4[ks * 8 + quad * 2 + 1];
        } else {
            p0 = make_float4(0.f, 0.f, 0.f, 0.f);
            p1 = p0;
        }
        short8 af;
        af[0] = (short)f2bf(p0.x); af[1] = (short)f2bf(p0.y);
        af[2] = (short)f2bf(p0.z); af[3] = (short)f2bf(p0.w);
        af[4] = (short)f2bf(p1.x); af[5] = (short)f2bf(p1.y);
        af[6] = (short)f2bf(p1.z); af[7] = (short)f2bf(p1.w);
        #pragma unroll
        for (int t = 0; t < 8; t++) {
            short8 bf = w1b[(t * 8 + ks) * 64 + lane];
            acc[t] = __builtin_amdgcn_mfma_f32_16x16x32_bf16(af, bf, acc[t], 0, 0, 0);
        }
    }

    // Epilogue: C layout col = l15, row = quad*4 + r (tile t == head t).
    const int rowC0 = bid * 64 + wv * 16 + quad * 4;
    #pragma unroll
    for (int t = 0; t < 8; t++) {
        float asw = att_s[t * 16 + l15];
        float adw = att_d[t * 16 + l15];
        #pragma unroll
        for (int r = 0; r < 4; r++) {
            int grow = rowC0 + r;
            float c = acc[t][r];
            if (grow < M) h1b[(size_t)grow * 128 + t * 16 + l15] = f2bf(c);
            float ps = c * asw;
            float pd = c * adw;
            ps += __shfl_xor(ps, 1, 64); ps += __shfl_xor(ps, 2, 64);
            ps += __shfl_xor(ps, 4, 64); ps += __shfl_xor(ps, 8, 64);
            pd += __shfl_xor(pd, 1, 64); pd += __shfl_xor(pd, 2, 64);
            pd += __shfl_xor(pd, 4, 64); pd += __shfl_xor(pd, 8, 64);
            if (l15 == 0 && grow < M) { a1s[grow * 8 + t] = ps; a1d[grow * 8 + t] = pd; }
        }
    }
}

// ---------------------------------------------------------------------------
// agg1: one wave per dst node, linked-list walk. Edge weight inline; h1
// gathered as bf16 (one uint = 2 cols per lane). Fused /denom, +b1, ELU.
// Writes h2 packed bf16 (uint = cols 2*lane, 2*lane+1).
// ---------------------------------------------------------------------------
__global__ void __launch_bounds__(256) agg1_kernel(
        const unsigned short* __restrict__ h1b, const float* __restrict__ a1s,
        const float* __restrict__ a1d, const int* __restrict__ head,
        const int* __restrict__ nxt, const int* __restrict__ ei,
        const float* __restrict__ b1, unsigned int* __restrict__ h2b, int n) {
    const int lane = threadIdx.x & 63;
    const int node = blockIdx.x * 4 + (threadIdx.x >> 6);
    if (node >= n) return;
    const int h = lane >> 3;
    const float ad = a1d[node * 8 + h];
    float l = 0.f, acc0 = 0.f, acc1 = 0.f;
    int e = head[node];
    while (e >= 0) {
        int en = nxt[e];               // issue chain load first
        int s = ei[e];
        float as = a1s[s * 8 + h];
        unsigned int u = *(const unsigned int*)(h1b + (size_t)s * 128 + lane * 2);
        float w = __expf(lrelu(as + ad));
        l += w;
        acc0 += w * bflo(u);
        acc1 += w * bfhi(u);
        e = en;
    }
    float inv = 1.f / (l + 1e-16f);
    float v0 = acc0 * inv + b1[lane * 2];
    float v1 = acc1 * inv + b1[lane * 2 + 1];
    v0 = (v0 > 0.f) ? v0 : expm1f(v0);
    v1 = (v1 > 0.f) ? v1 : expm1f(v1);
    h2b[(size_t)node * 64 + lane] = (unsigned int)f2bf(v0) | ((unsigned int)f2bf(v1) << 16);
}

// ---------------------------------------------------------------------------
// GEMM2 (MFMA bf16): t2b = bf16(h2[N,128] @ W2[128,64]); fused a2s/a2d dots
// (single head => sum over all 64 cols, so per-tile partials accumulate).
// 4 waves/block, wave = 16 rows x 64 cols (4 tiles), no LDS.
// ---------------------------------------------------------------------------
__global__ void __launch_bounds__(256) gemm2_kernel(
        const short8* __restrict__ h2f, const short8* __restrict__ w2b,
        const float* __restrict__ att_s, const float* __restrict__ att_d,
        unsigned short* __restrict__ t2b, float* __restrict__ a2s, float* __restrict__ a2d,
        int n) {
    const int lane = threadIdx.x & 63;
    const int wv = threadIdx.x >> 6;
    const int quad = lane >> 4;
    const int l15 = lane & 15;

    const int rowA = blockIdx.x * 64 + wv * 16 + l15;
    const bool rowAok = rowA < n;

    floatx4 acc[4];
    #pragma unroll
    for (int t = 0; t < 4; t++) acc[t] = (floatx4){0.f, 0.f, 0.f, 0.f};

    #pragma unroll
    for (int ks = 0; ks < 4; ks++) {
        short8 af = {0, 0, 0, 0, 0, 0, 0, 0};
        if (rowAok) af = h2f[(size_t)rowA * 16 + ks * 4 + quad];
        #pragma unroll
        for (int t = 0; t < 4; t++) {
            short8 bf = w2b[(t * 4 + ks) * 64 + lane];
            acc[t] = __builtin_amdgcn_mfma_f32_16x16x32_bf16(af, bf, acc[t], 0, 0, 0);
        }
    }

    const int rowC0 = blockIdx.x * 64 + wv * 16 + quad * 4;
    float asw[4], adw[4];
    #pragma unroll
    for (int t = 0; t < 4; t++) {
        asw[t] = att_s[t * 16 + l15];
        adw[t] = att_d[t * 16 + l15];
    }
    #pragma unroll
    for (int r = 0; r < 4; r++) {
        int grow = rowC0 + r;
        bool ok = grow < n;
        float ps = 0.f, pd = 0.f;
        #pragma unroll
        for (int t = 0; t < 4; t++) {
            float c = acc[t][r];
            if (ok) t2b[(size_t)grow * 64 + t * 16 + l15] = f2bf(c);
            ps += c * asw[t];
            pd += c * adw[t];
        }
        ps += __shfl_xor(ps, 1, 64); ps += __shfl_xor(ps, 2, 64);
        ps += __shfl_xor(ps, 4, 64); ps += __shfl_xor(ps, 8, 64);
        pd += __shfl_xor(pd, 1, 64); pd += __shfl_xor(pd, 2, 64);
        pd += __shfl_xor(pd, 4, 64); pd += __shfl_xor(pd, 8, 64);
        if (l15 == 0 && ok) { a2s[grow] = ps; a2d[grow] = pd; }
    }
}

// ---------------------------------------------------------------------------
// agg2: one wave per dst node, lane = channel, linked-list walk, bf16 t2
// gather. Fused bias + log_softmax across the 64 lanes.
// ---------------------------------------------------------------------------
__global__ void __launch_bounds__(256) agg2_kernel(
        const unsigned short* __restrict__ t2b, const float* __restrict__ a2s,
        const float* __restrict__ a2d, const int* __restrict__ head,
        const int* __restrict__ nxt, const int* __restrict__ ei,
        const float* __restrict__ b2, float* __restrict__ out, int n) {
    const int lane = threadIdx.x & 63;
    const int node = blockIdx.x * 4 + (threadIdx.x >> 6);
    if (node >= n) return;
    const float ad = a2d[node];
    float l = 0.f, acc = 0.f;
    int e = head[node];
    while (e >= 0) {
        int en = nxt[e];
        int s = ei[e];
        float as = a2s[s];
        unsigned short u = t2b[(size_t)s * 64 + lane];
        float w = __expf(lrelu(as + ad));
        l += w;
        acc += w * __uint_as_float(((unsigned int)u) << 16);
        e = en;
    }
    float v = acc / (l + 1e-16f) + b2[lane];
    float mx = v;
    #pragma unroll
    for (int off = 32; off >= 1; off >>= 1) mx = fmaxf(mx, __shfl_xor(mx, off, 64));
    float ex = expf(v - mx);
    float s2 = ex;
    #pragma unroll
    for (int off = 32; off >= 1; off >>= 1) s2 += __shfl_xor(s2, off, 64);
    out[(size_t)node * 64 + lane] = v - mx - logf(s2);
}

// ---------------------------------------------------------------------------

extern "C" void kernel_launch(void* const* d_in, const int* in_sizes, int n_in,
                              void* d_out, int out_size, void* d_ws, size_t ws_size,
                              hipStream_t stream) {
    const float* x     = (const float*)d_in[0];
    const int*   ei    = (const int*)d_in[1];
    const float* W1    = (const float*)d_in[2];
    const float* att1s = (const float*)d_in[3];
    const float* att1d = (const float*)d_in[4];
    const float* b1    = (const float*)d_in[5];
    const float* W2    = (const float*)d_in[6];
    const float* att2s = (const float*)d_in[7];
    const float* att2d = (const float*)d_in[8];
    const float* b2    = (const float*)d_in[9];
    float* out = (float*)d_out;

    const int N = N_NODES, E = N_EDGES;

    char* p = (char*)d_ws;
    auto take = [&](size_t bytes) {
        char* r = p;
        p += (bytes + 255) & ~(size_t)255;
        return (void*)r;
    };
    int*            head = (int*)take((size_t)N * 4);
    int*            nxt  = (int*)take((size_t)E * 4);
    unsigned short* w1b  = (unsigned short*)take(64 * 64 * 16);            // 64 KB
    unsigned short* w2b  = (unsigned short*)take(16 * 64 * 16);            // 16 KB
    unsigned short* h1b  = (unsigned short*)take((size_t)N * 128 * 2);     // bf16
    float*          a1s  = (float*)take((size_t)N * 8 * 4);                // reused a2s
    float*          a1d  = (float*)take((size_t)N * 8 * 4);                // reused a2d
    unsigned int*   h2b  = (unsigned int*)take((size_t)N * 64 * 4);        // packed bf16
    unsigned short* t2b  = (unsigned short*)take((size_t)N * 64 * 2);      // bf16
    float* a2s = a1s;
    float* a2d = a1d;

    hipMemsetAsync(head, 0xFF, (size_t)N * 4, stream);   // -1 sentinels

    prep_kernel<<<20, 256, 0, stream>>>(W1, W2, w1b, w2b);
    gemm1_link_kernel<<<GEMM1_BLOCKS + LINK_BLOCKS, 256, 0, stream>>>(
        x, (const short8*)w1b, att1s, att1d, h1b, a1s, a1d, ei, head, nxt);
    agg1_kernel<<<(N + 3) / 4, 256, 0, stream>>>(h1b, a1s, a1d, head, nxt, ei, b1, h2b, N);
    gemm2_kernel<<<(N + 63) / 64, 256, 0, stream>>>((const short8*)h2b, (const short8*)w2b,
                                                    att2s, att2d, t2b, a2s, a2d, N);
    agg2_kernel<<<(N + 3) / 4, 256, 0, stream>>>(t2b, a2s, a2d, head, nxt, ei, b2, out, N);
}

// Round 6
// 580.391 us; speedup vs baseline: 1.5877x; 1.0910x over previous
//
#include <hip/hip_runtime.h>
#include <math.h>

#define N_NODES 100000
#define N_EDGES 1600000
#define GEMM1_BLOCKS ((N_NODES + 63) / 64)    // 1563
#define LINK_BLOCKS  ((N_EDGES + 255) / 256)  // 6250

typedef __attribute__((ext_vector_type(8))) short short8;    // 8 x bf16 bits
typedef __attribute__((ext_vector_type(4))) float floatx4;   // MFMA acc

__device__ __forceinline__ float lrelu(float v) {
    return (v > 0.f) ? v : 0.2f * v;
}

__device__ __forceinline__ unsigned short f2bf(float f) {
    unsigned int u = __float_as_uint(f);
    u += 0x7fff + ((u >> 16) & 1);   // round-to-nearest-even
    return (unsigned short)(u >> 16);
}

__device__ __forceinline__ float bflo(unsigned int u) { return __uint_as_float(u << 16); }
__device__ __forceinline__ float bfhi(unsigned int u) { return __uint_as_float(u & 0xffff0000u); }

// ---------------------------------------------------------------------------
// prep: swizzle W1/W2 into bf16 MFMA B-fragment order (see r4 comments).
// ---------------------------------------------------------------------------
__global__ void prep_kernel(const float* __restrict__ W1, const float* __restrict__ W2,
                            unsigned short* __restrict__ w1b, unsigned short* __restrict__ w2b) {
    int idx = blockIdx.x * 256 + threadIdx.x;
    if (idx < 4096) {
        int lane = idx & 63;
        int ts = idx >> 6;
        int t = ts >> 3, ks = ts & 7;
        int quad = lane >> 4, l15 = lane & 15;
        int kbase = ks * 32 + quad * 8;
        unsigned short o[8];
        #pragma unroll
        for (int j = 0; j < 8; j++)
            o[j] = f2bf(W1[(size_t)(kbase + j) * 128 + t * 16 + l15]);
        uint4 pk;
        pk.x = o[0] | ((unsigned int)o[1] << 16);
        pk.y = o[2] | ((unsigned int)o[3] << 16);
        pk.z = o[4] | ((unsigned int)o[5] << 16);
        pk.w = o[6] | ((unsigned int)o[7] << 16);
        ((uint4*)w1b)[idx] = pk;
    } else if (idx < 4096 + 1024) {
        int idx2 = idx - 4096;
        int lane = idx2 & 63;
        int ts = idx2 >> 6;
        int t = ts >> 2, ks = ts & 3;
        int quad = lane >> 4, l15 = lane & 15;
        int kbase = ks * 32 + quad * 8;
        unsigned short o[8];
        #pragma unroll
        for (int j = 0; j < 8; j++)
            o[j] = f2bf(W2[(size_t)(kbase + j) * 64 + t * 16 + l15]);
        uint4 pk;
        pk.x = o[0] | ((unsigned int)o[1] << 16);
        pk.y = o[2] | ((unsigned int)o[3] << 16);
        pk.z = o[4] | ((unsigned int)o[5] << 16);
        pk.w = o[6] | ((unsigned int)o[7] << 16);
        ((uint4*)w2b)[idx2] = pk;
    }
}

// ---------------------------------------------------------------------------
// Fused GEMM1 (MFMA bf16) + linked-list build + degree count.
// Blocks [0, GEMM1_BLOCKS): h1b = bf16(x @ W1), fused a1s/a1d head dots.
// Blocks [GEMM1_BLOCKS, +LINK_BLOCKS): rec8[e] = {atomicExch(&head[dst],e), src}
//   (8 B coalesced) + atomicAdd(deg[dst]). head pre-memset -1, deg 0.
// ---------------------------------------------------------------------------
__global__ void __launch_bounds__(256) gemm1_link_kernel(
        const float* __restrict__ x, const short8* __restrict__ w1b,
        const float* __restrict__ att_s, const float* __restrict__ att_d,
        unsigned short* __restrict__ h1b, float* __restrict__ a1s, float* __restrict__ a1d,
        const int* __restrict__ ei, int* __restrict__ head, int2* __restrict__ rec8,
        int* __restrict__ deg) {
    const int bid = blockIdx.x;
    if (bid >= GEMM1_BLOCKS) {
        int e = (bid - GEMM1_BLOCKS) * 256 + threadIdx.x;
        if (e < N_EDGES) {
            int s = ei[e];
            int d = ei[N_EDGES + e];
            int old = atomicExch(&head[d], e);
            rec8[e] = make_int2(old, s);
            atomicAdd(&deg[d], 1);
        }
        return;
    }
    const int lane = threadIdx.x & 63;
    const int wv = threadIdx.x >> 6;
    const int quad = lane >> 4;
    const int l15 = lane & 15;
    const int M = N_NODES;

    const int rowA = bid * 64 + wv * 16 + l15;
    const bool rowAok = rowA < M;
    const float4* xrow4 = (const float4*)(x + (size_t)rowA * 256);

    floatx4 acc[8];
    #pragma unroll
    for (int t = 0; t < 8; t++) acc[t] = (floatx4){0.f, 0.f, 0.f, 0.f};

    #pragma unroll
    for (int ks = 0; ks < 8; ks++) {
        float4 p0, p1;
        if (rowAok) {
            p0 = xrow4[ks * 8 + quad * 2];
            p1 = xrow4[ks * 8 + quad * 2 + 1];
        } else {
            p0 = make_float4(0.f, 0.f, 0.f, 0.f);
            p1 = p0;
        }
        short8 af;
        af[0] = (short)f2bf(p0.x); af[1] = (short)f2bf(p0.y);
        af[2] = (short)f2bf(p0.z); af[3] = (short)f2bf(p0.w);
        af[4] = (short)f2bf(p1.x); af[5] = (short)f2bf(p1.y);
        af[6] = (short)f2bf(p1.z); af[7] = (short)f2bf(p1.w);
        #pragma unroll
        for (int t = 0; t < 8; t++) {
            short8 bf = w1b[(t * 8 + ks) * 64 + lane];
            acc[t] = __builtin_amdgcn_mfma_f32_16x16x32_bf16(af, bf, acc[t], 0, 0, 0);
        }
    }

    // Epilogue: C layout col = l15, row = quad*4 + r (tile t == head t).
    const int rowC0 = bid * 64 + wv * 16 + quad * 4;
    #pragma unroll
    for (int t = 0; t < 8; t++) {
        float asw = att_s[t * 16 + l15];
        float adw = att_d[t * 16 + l15];
        #pragma unroll
        for (int r = 0; r < 4; r++) {
            int grow = rowC0 + r;
            float c = acc[t][r];
            if (grow < M) h1b[(size_t)grow * 128 + t * 16 + l15] = f2bf(c);
            float ps = c * asw;
            float pd = c * adw;
            ps += __shfl_xor(ps, 1, 64); ps += __shfl_xor(ps, 2, 64);
            ps += __shfl_xor(ps, 4, 64); ps += __shfl_xor(ps, 8, 64);
            pd += __shfl_xor(pd, 1, 64); pd += __shfl_xor(pd, 2, 64);
            pd += __shfl_xor(pd, 4, 64); pd += __shfl_xor(pd, 8, 64);
            if (l15 == 0 && grow < M) { a1s[grow * 8 + t] = ps; a1d[grow * 8 + t] = pd; }
        }
    }
}

// ---------------------------------------------------------------------------
// alloc: rowstart = exclusive prefix sum of deg (wave scan + one atomic/wave).
// ---------------------------------------------------------------------------
__global__ void alloc_kernel(const int* __restrict__ deg, int* __restrict__ rowstart,
                             int* __restrict__ counter, int n) {
    int i = blockIdx.x * 256 + threadIdx.x;
    int lane = threadIdx.x & 63;
    int d = (i < n) ? deg[i] : 0;
    int pre = d;
    #pragma unroll
    for (int off = 1; off < 64; off <<= 1) {
        int v = __shfl_up(pre, off, 64);
        if (lane >= off) pre += v;
    }
    int total = __shfl(pre, 63, 64);
    int base = 0;
    if (lane == 63) base = atomicAdd(counter, total);
    base = __shfl(base, 63, 64);
    if (i < n) rowstart[i] = base + pre - d;
}

// ---------------------------------------------------------------------------
// flatten: thread-per-node chain walk -> csr_src. 256 independent chains per
// block hide the chase latency; per-lane writes are sequential (runs pack
// into full lines in L2 -> no random-scatter write amplification).
// ---------------------------------------------------------------------------
__global__ void flatten_kernel(const int* __restrict__ head, const int2* __restrict__ rec8,
                               const int* __restrict__ rowstart, int* __restrict__ csr_src,
                               int n) {
    int node = blockIdx.x * 256 + threadIdx.x;
    if (node >= n) return;
    int e = head[node];
    int c = rowstart[node];
    while (e >= 0) {
        int2 r = rec8[e];
        csr_src[c++] = r.y;
        e = r.x;
    }
}

// ---------------------------------------------------------------------------
// agg1: one wave per dst node over CSR, 2-way unrolled (independent loads).
// Edge weight inline; h1 gathered as bf16 (uint = 2 cols per lane).
// Fused /denom, +b1, ELU. Writes h2 packed bf16.
// ---------------------------------------------------------------------------
__global__ void __launch_bounds__(256) agg1_kernel(
        const unsigned short* __restrict__ h1b, const float* __restrict__ a1s,
        const float* __restrict__ a1d, const int* __restrict__ rowstart,
        const int* __restrict__ deg, const int* __restrict__ csr_src,
        const float* __restrict__ b1, unsigned int* __restrict__ h2b, int n) {
    const int lane = threadIdx.x & 63;
    const int node = blockIdx.x * 4 + (threadIdx.x >> 6);
    if (node >= n) return;
    const int h = lane >> 3;
    const int start = rowstart[node];
    const int d = deg[node];
    const float ad = a1d[node * 8 + h];
    float l = 0.f, acc0 = 0.f, acc1 = 0.f;
    int i = 0;
    for (; i + 2 <= d; i += 2) {
        int s0 = csr_src[start + i];
        int s1 = csr_src[start + i + 1];
        float as0 = a1s[s0 * 8 + h];
        float as1 = a1s[s1 * 8 + h];
        unsigned int u0 = *(const unsigned int*)(h1b + (size_t)s0 * 128 + lane * 2);
        unsigned int u1 = *(const unsigned int*)(h1b + (size_t)s1 * 128 + lane * 2);
        float e0 = __expf(lrelu(as0 + ad));
        float e1 = __expf(lrelu(as1 + ad));
        l += e0 + e1;
        acc0 += e0 * bflo(u0) + e1 * bflo(u1);
        acc1 += e0 * bfhi(u0) + e1 * bfhi(u1);
    }
    if (i < d) {
        int s0 = csr_src[start + i];
        float as0 = a1s[s0 * 8 + h];
        unsigned int u0 = *(const unsigned int*)(h1b + (size_t)s0 * 128 + lane * 2);
        float e0 = __expf(lrelu(as0 + ad));
        l += e0;
        acc0 += e0 * bflo(u0);
        acc1 += e0 * bfhi(u0);
    }
    float inv = 1.f / (l + 1e-16f);
    float v0 = acc0 * inv + b1[lane * 2];
    float v1 = acc1 * inv + b1[lane * 2 + 1];
    v0 = (v0 > 0.f) ? v0 : expm1f(v0);
    v1 = (v1 > 0.f) ? v1 : expm1f(v1);
    h2b[(size_t)node * 64 + lane] = (unsigned int)f2bf(v0) | ((unsigned int)f2bf(v1) << 16);
}

// ---------------------------------------------------------------------------
// GEMM2 (MFMA bf16): t2b = bf16(h2[N,128] @ W2[128,64]); fused a2s/a2d dots.
// ---------------------------------------------------------------------------
__global__ void __launch_bounds__(256) gemm2_kernel(
        const short8* __restrict__ h2f, const short8* __restrict__ w2b,
        const float* __restrict__ att_s, const float* __restrict__ att_d,
        unsigned short* __restrict__ t2b, float* __restrict__ a2s, float* __restrict__ a2d,
        int n) {
    const int lane = threadIdx.x & 63;
    const int wv = threadIdx.x >> 6;
    const int quad = lane >> 4;
    const int l15 = lane & 15;

    const int rowA = blockIdx.x * 64 + wv * 16 + l15;
    const bool rowAok = rowA < n;

    floatx4 acc[4];
    #pragma unroll
    for (int t = 0; t < 4; t++) acc[t] = (floatx4){0.f, 0.f, 0.f, 0.f};

    #pragma unroll
    for (int ks = 0; ks < 4; ks++) {
        short8 af = {0, 0, 0, 0, 0, 0, 0, 0};
        if (rowAok) af = h2f[(size_t)rowA * 16 + ks * 4 + quad];
        #pragma unroll
        for (int t = 0; t < 4; t++) {
            short8 bf = w2b[(t * 4 + ks) * 64 + lane];
            acc[t] = __builtin_amdgcn_mfma_f32_16x16x32_bf16(af, bf, acc[t], 0, 0, 0);
        }
    }

    const int rowC0 = blockIdx.x * 64 + wv * 16 + quad * 4;
    float asw[4], adw[4];
    #pragma unroll
    for (int t = 0; t < 4; t++) {
        asw[t] = att_s[t * 16 + l15];
        adw[t] = att_d[t * 16 + l15];
    }
    #pragma unroll
    for (int r = 0; r < 4; r++) {
        int grow = rowC0 + r;
        bool ok = grow < n;
        float ps = 0.f, pd = 0.f;
        #pragma unroll
        for (int t = 0; t < 4; t++) {
            float c = acc[t][r];
            if (ok) t2b[(size_t)grow * 64 + t * 16 + l15] = f2bf(c);
            ps += c * asw[t];
            pd += c * adw[t];
        }
        ps += __shfl_xor(ps, 1, 64); ps += __shfl_xor(ps, 2, 64);
        ps += __shfl_xor(ps, 4, 64); ps += __shfl_xor(ps, 8, 64);
        pd += __shfl_xor(pd, 1, 64); pd += __shfl_xor(pd, 2, 64);
        pd += __shfl_xor(pd, 4, 64); pd += __shfl_xor(pd, 8, 64);
        if (l15 == 0 && ok) { a2s[grow] = ps; a2d[grow] = pd; }
    }
}

// ---------------------------------------------------------------------------
// agg2: one wave per dst node over CSR, 2-way unrolled, bf16 t2 gather.
// Fused bias + log_softmax across the 64 lanes.
// ---------------------------------------------------------------------------
__global__ void __launch_bounds__(256) agg2_kernel(
        const unsigned short* __restrict__ t2b, const float* __restrict__ a2s,
        const float* __restrict__ a2d, const int* __restrict__ rowstart,
        const int* __restrict__ deg, const int* __restrict__ csr_src,
        const float* __restrict__ b2, float* __restrict__ out, int n) {
    const int lane = threadIdx.x & 63;
    const int node = blockIdx.x * 4 + (threadIdx.x >> 6);
    if (node >= n) return;
    const int start = rowstart[node];
    const int d = deg[node];
    const float ad = a2d[node];
    float l = 0.f, acc = 0.f;
    int i = 0;
    for (; i + 2 <= d; i += 2) {
        int s0 = csr_src[start + i];
        int s1 = csr_src[start + i + 1];
        float as0 = a2s[s0];
        float as1 = a2s[s1];
        unsigned short u0 = t2b[(size_t)s0 * 64 + lane];
        unsigned short u1 = t2b[(size_t)s1 * 64 + lane];
        float e0 = __expf(lrelu(as0 + ad));
        float e1 = __expf(lrelu(as1 + ad));
        l += e0 + e1;
        acc += e0 * __uint_as_float(((unsigned int)u0) << 16)
             + e1 * __uint_as_float(((unsigned int)u1) << 16);
    }
    if (i < d) {
        int s0 = csr_src[start + i];
        float as0 = a2s[s0];
        unsigned short u0 = t2b[(size_t)s0 * 64 + lane];
        float e0 = __expf(lrelu(as0 + ad));
        l += e0;
        acc += e0 * __uint_as_float(((unsigned int)u0) << 16);
    }
    float v = acc / (l + 1e-16f) + b2[lane];
    float mx = v;
    #pragma unroll
    for (int off = 32; off >= 1; off >>= 1) mx = fmaxf(mx, __shfl_xor(mx, off, 64));
    float ex = expf(v - mx);
    float s2 = ex;
    #pragma unroll
    for (int off = 32; off >= 1; off >>= 1) s2 += __shfl_xor(s2, off, 64);
    out[(size_t)node * 64 + lane] = v - mx - logf(s2);
}

// ---------------------------------------------------------------------------

extern "C" void kernel_launch(void* const* d_in, const int* in_sizes, int n_in,
                              void* d_out, int out_size, void* d_ws, size_t ws_size,
                              hipStream_t stream) {
    const float* x     = (const float*)d_in[0];
    const int*   ei    = (const int*)d_in[1];
    const float* W1    = (const float*)d_in[2];
    const float* att1s = (const float*)d_in[3];
    const float* att1d = (const float*)d_in[4];
    const float* b1    = (const float*)d_in[5];
    const float* W2    = (const float*)d_in[6];
    const float* att2s = (const float*)d_in[7];
    const float* att2d = (const float*)d_in[8];
    const float* b2    = (const float*)d_in[9];
    float* out = (float*)d_out;

    const int N = N_NODES, E = N_EDGES;

    char* p = (char*)d_ws;
    auto take = [&](size_t bytes) {
        char* r = p;
        p += (bytes + 255) & ~(size_t)255;
        return (void*)r;
    };
    int*            head     = (int*)take((size_t)N * 4);
    int*            deg      = (int*)take((size_t)N * 4);
    int*            rowstart = (int*)take((size_t)N * 4);
    int*            counter  = (int*)take(256);
    int2*           rec8     = (int2*)take((size_t)E * 8);
    int*            csr_src  = (int*)take((size_t)E * 4);
    unsigned short* w1b      = (unsigned short*)take(64 * 64 * 16);           // 64 KB
    unsigned short* w2b      = (unsigned short*)take(16 * 64 * 16);           // 16 KB
    unsigned short* h1b      = (unsigned short*)take((size_t)N * 128 * 2);    // bf16
    float*          a1s      = (float*)take((size_t)N * 8 * 4);               // reused a2s
    float*          a1d      = (float*)take((size_t)N * 8 * 4);               // reused a2d
    unsigned int*   h2b      = (unsigned int*)take((size_t)N * 64 * 4);       // packed bf16
    unsigned short* t2b      = (unsigned short*)take((size_t)N * 64 * 2);     // bf16
    float* a2s = a1s;
    float* a2d = a1d;

    hipMemsetAsync(head, 0xFF, (size_t)N * 4, stream);   // -1 sentinels
    hipMemsetAsync(deg, 0, (size_t)N * 4, stream);
    hipMemsetAsync(counter, 0, 4, stream);

    prep_kernel<<<20, 256, 0, stream>>>(W1, W2, w1b, w2b);
    gemm1_link_kernel<<<GEMM1_BLOCKS + LINK_BLOCKS, 256, 0, stream>>>(
        x, (const short8*)w1b, att1s, att1d, h1b, a1s, a1d, ei, head, rec8, deg);
    alloc_kernel<<<(N + 255) / 256, 256, 0, stream>>>(deg, rowstart, counter, N);
    flatten_kernel<<<(N + 255) / 256, 256, 0, stream>>>(head, rec8, rowstart, csr_src, N);
    agg1_kernel<<<(N + 3) / 4, 256, 0, stream>>>(h1b, a1s, a1d, rowstart, deg, csr_src,
                                                 b1, h2b, N);
    gemm2_kernel<<<(N + 63) / 64, 256, 0, stream>>>((const short8*)h2b, (const short8*)w2b,
                                                    att2s, att2d, t2b, a2s, a2d, N);
    agg2_kernel<<<(N + 3) / 4, 256, 0, stream>>>(t2b, a2s, a2d, rowstart, deg, csr_src,
                                                 b2, out, N);
}

// Round 7
// 488.152 us; speedup vs baseline: 1.8876x; 1.1890x over previous
//
#include <hip/hip_runtime.h>
#include <math.h>

#define N_NODES 100000
#define N_EDGES 1600000
#define GEMM1_BLOCKS ((N_NODES + 63) / 64)        // 1563
#define FUSED_BLOCKS (GEMM1_BLOCKS * 5)           // 7815: 1563 gemm + 6252 link

typedef __attribute__((ext_vector_type(8))) short short8;    // 8 x bf16 bits
typedef __attribute__((ext_vector_type(4))) float floatx4;   // MFMA acc

__device__ __forceinline__ float lrelu(float v) {
    return (v > 0.f) ? v : 0.2f * v;
}

__device__ __forceinline__ unsigned short f2bf(float f) {
    unsigned int u = __float_as_uint(f);
    u += 0x7fff + ((u >> 16) & 1);   // round-to-nearest-even
    return (unsigned short)(u >> 16);
}

__device__ __forceinline__ float bflo(unsigned int u) { return __uint_as_float(u << 16); }
__device__ __forceinline__ float bfhi(unsigned int u) { return __uint_as_float(u & 0xffff0000u); }

// ---------------------------------------------------------------------------
// prep: swizzle W1/W2 into bf16 MFMA B-fragment order.
// ---------------------------------------------------------------------------
__global__ void prep_kernel(const float* __restrict__ W1, const float* __restrict__ W2,
                            unsigned short* __restrict__ w1b, unsigned short* __restrict__ w2b) {
    int idx = blockIdx.x * 256 + threadIdx.x;
    if (idx < 4096) {
        int lane = idx & 63;
        int ts = idx >> 6;
        int t = ts >> 3, ks = ts & 7;
        int quad = lane >> 4, l15 = lane & 15;
        int kbase = ks * 32 + quad * 8;
        unsigned short o[8];
        #pragma unroll
        for (int j = 0; j < 8; j++)
            o[j] = f2bf(W1[(size_t)(kbase + j) * 128 + t * 16 + l15]);
        uint4 pk;
        pk.x = o[0] | ((unsigned int)o[1] << 16);
        pk.y = o[2] | ((unsigned int)o[3] << 16);
        pk.z = o[4] | ((unsigned int)o[5] << 16);
        pk.w = o[6] | ((unsigned int)o[7] << 16);
        ((uint4*)w1b)[idx] = pk;
    } else if (idx < 4096 + 1024) {
        int idx2 = idx - 4096;
        int lane = idx2 & 63;
        int ts = idx2 >> 6;
        int t = ts >> 2, ks = ts & 3;
        int quad = lane >> 4, l15 = lane & 15;
        int kbase = ks * 32 + quad * 8;
        unsigned short o[8];
        #pragma unroll
        for (int j = 0; j < 8; j++)
            o[j] = f2bf(W2[(size_t)(kbase + j) * 64 + t * 16 + l15]);
        uint4 pk;
        pk.x = o[0] | ((unsigned int)o[1] << 16);
        pk.y = o[2] | ((unsigned int)o[3] << 16);
        pk.z = o[4] | ((unsigned int)o[5] << 16);
        pk.w = o[6] | ((unsigned int)o[7] << 16);
        ((uint4*)w2b)[idx2] = pk;
    }
}

// ---------------------------------------------------------------------------
// Fused GEMM1 (MFMA bf16) + linked-list build, roles INTERLEAVED (bid % 5):
// 1 gemm block per 4 link blocks, so atomic latency hides under MFMA.
// link: rec8[e] = {atomicExch(&head[dst], e), src}  (single atomic/edge;
// degree is recovered later by a chain-count walk). head pre-memset -1.
// ---------------------------------------------------------------------------
__global__ void __launch_bounds__(256) gemm1_link_kernel(
        const float* __restrict__ x, const short8* __restrict__ w1b,
        const float* __restrict__ att_s, const float* __restrict__ att_d,
        unsigned short* __restrict__ h1b, float* __restrict__ a1s, float* __restrict__ a1d,
        const int* __restrict__ ei, int* __restrict__ head, int2* __restrict__ rec8) {
    const int bid = blockIdx.x;
    if (bid % 5 != 0) {
        int lid = bid - bid / 5 - 1;               // 0..6251
        int e = lid * 256 + threadIdx.x;
        if (e < N_EDGES) {
            int s = ei[e];
            int d = ei[N_EDGES + e];
            int old = atomicExch(&head[d], e);
            rec8[e] = make_int2(old, s);
        }
        return;
    }
    const int gid = bid / 5;                        // 0..1562
    const int lane = threadIdx.x & 63;
    const int wv = threadIdx.x >> 6;
    const int quad = lane >> 4;
    const int l15 = lane & 15;
    const int M = N_NODES;

    const int rowA = gid * 64 + wv * 16 + l15;
    const bool rowAok = rowA < M;
    const float4* xrow4 = (const float4*)(x + (size_t)rowA * 256);

    floatx4 acc[8];
    #pragma unroll
    for (int t = 0; t < 8; t++) acc[t] = (floatx4){0.f, 0.f, 0.f, 0.f};

    #pragma unroll
    for (int ks = 0; ks < 8; ks++) {
        float4 p0, p1;
        if (rowAok) {
            p0 = xrow4[ks * 8 + quad * 2];
            p1 = xrow4[ks * 8 + quad * 2 + 1];
        } else {
            p0 = make_float4(0.f, 0.f, 0.f, 0.f);
            p1 = p0;
        }
        short8 af;
        af[0] = (short)f2bf(p0.x); af[1] = (short)f2bf(p0.y);
        af[2] = (short)f2bf(p0.z); af[3] = (short)f2bf(p0.w);
        af[4] = (short)f2bf(p1.x); af[5] = (short)f2bf(p1.y);
        af[6] = (short)f2bf(p1.z); af[7] = (short)f2bf(p1.w);
        #pragma unroll
        for (int t = 0; t < 8; t++) {
            short8 bf = w1b[(t * 8 + ks) * 64 + lane];
            acc[t] = __builtin_amdgcn_mfma_f32_16x16x32_bf16(af, bf, acc[t], 0, 0, 0);
        }
    }

    // Epilogue: C layout col = l15, row = quad*4 + r (tile t == head t).
    const int rowC0 = gid * 64 + wv * 16 + quad * 4;
    #pragma unroll
    for (int t = 0; t < 8; t++) {
        float asw = att_s[t * 16 + l15];
        float adw = att_d[t * 16 + l15];
        #pragma unroll
        for (int r = 0; r < 4; r++) {
            int grow = rowC0 + r;
            float c = acc[t][r];
            if (grow < M) h1b[(size_t)grow * 128 + t * 16 + l15] = f2bf(c);
            float ps = c * asw;
            float pd = c * adw;
            ps += __shfl_xor(ps, 1, 64); ps += __shfl_xor(ps, 2, 64);
            ps += __shfl_xor(ps, 4, 64); ps += __shfl_xor(ps, 8, 64);
            pd += __shfl_xor(pd, 1, 64); pd += __shfl_xor(pd, 2, 64);
            pd += __shfl_xor(pd, 4, 64); pd += __shfl_xor(pd, 8, 64);
            if (l15 == 0 && grow < M) { a1s[grow * 8 + t] = ps; a1d[grow * 8 + t] = pd; }
        }
    }
}

// ---------------------------------------------------------------------------
// count_alloc: thread-per-node chain-count walk (reads rec8[].x only),
// then wave prefix-scan -> rowstart, plain store of deg. One chase pass,
// zero per-edge atomics.
// ---------------------------------------------------------------------------
__global__ void count_alloc_kernel(const int* __restrict__ head, const int2* __restrict__ rec8,
                                   int* __restrict__ rowstart, int* __restrict__ deg,
                                   int* __restrict__ counter, int n) {
    int i = blockIdx.x * 256 + threadIdx.x;
    int lane = threadIdx.x & 63;
    int c = 0;
    if (i < n) {
        int e = head[i];
        while (e >= 0) {
            e = ((const int*)rec8)[(size_t)e * 2];   // nxt
            c++;
        }
    }
    int d = c;
    int pre = d;
    #pragma unroll
    for (int off = 1; off < 64; off <<= 1) {
        int v = __shfl_up(pre, off, 64);
        if (lane >= off) pre += v;
    }
    int total = __shfl(pre, 63, 64);
    int base = 0;
    if (lane == 63) base = atomicAdd(counter, total);
    base = __shfl(base, 63, 64);
    if (i < n) {
        rowstart[i] = base + pre - d;
        deg[i] = d;
    }
}

// ---------------------------------------------------------------------------
// flatten: thread-per-node chain walk -> csr_src (sequential per-node writes
// pack into full lines; rec8 is LLC-hot after count_alloc).
// ---------------------------------------------------------------------------
__global__ void flatten_kernel(const int* __restrict__ head, const int2* __restrict__ rec8,
                               const int* __restrict__ rowstart, int* __restrict__ csr_src,
                               int n) {
    int node = blockIdx.x * 256 + threadIdx.x;
    if (node >= n) return;
    int e = head[node];
    int c = rowstart[node];
    while (e >= 0) {
        int2 r = rec8[e];
        csr_src[c++] = r.y;
        e = r.x;
    }
}

// ---------------------------------------------------------------------------
// agg1: one wave per dst node over CSR, 4-way unrolled (independent loads
// for MLP). Edge weight inline; h1 gathered as bf16. Fused /denom, +b1, ELU.
// Writes h2 packed bf16.
// ---------------------------------------------------------------------------
__global__ void __launch_bounds__(256) agg1_kernel(
        const unsigned short* __restrict__ h1b, const float* __restrict__ a1s,
        const float* __restrict__ a1d, const int* __restrict__ rowstart,
        const int* __restrict__ deg, const int* __restrict__ csr_src,
        const float* __restrict__ b1, unsigned int* __restrict__ h2b, int n) {
    const int lane = threadIdx.x & 63;
    const int node = blockIdx.x * 4 + (threadIdx.x >> 6);
    if (node >= n) return;
    const int h = lane >> 3;
    const int start = rowstart[node];
    const int d = deg[node];
    const float ad = a1d[node * 8 + h];
    float l = 0.f, acc0 = 0.f, acc1 = 0.f;
    int i = 0;
    for (; i + 4 <= d; i += 4) {
        int s0 = csr_src[start + i];
        int s1 = csr_src[start + i + 1];
        int s2 = csr_src[start + i + 2];
        int s3 = csr_src[start + i + 3];
        float as0 = a1s[s0 * 8 + h];
        float as1 = a1s[s1 * 8 + h];
        float as2 = a1s[s2 * 8 + h];
        float as3 = a1s[s3 * 8 + h];
        unsigned int u0 = *(const unsigned int*)(h1b + (size_t)s0 * 128 + lane * 2);
        unsigned int u1 = *(const unsigned int*)(h1b + (size_t)s1 * 128 + lane * 2);
        unsigned int u2 = *(const unsigned int*)(h1b + (size_t)s2 * 128 + lane * 2);
        unsigned int u3 = *(const unsigned int*)(h1b + (size_t)s3 * 128 + lane * 2);
        float e0 = __expf(lrelu(as0 + ad));
        float e1 = __expf(lrelu(as1 + ad));
        float e2 = __expf(lrelu(as2 + ad));
        float e3 = __expf(lrelu(as3 + ad));
        l += (e0 + e1) + (e2 + e3);
        acc0 += e0 * bflo(u0) + e1 * bflo(u1) + e2 * bflo(u2) + e3 * bflo(u3);
        acc1 += e0 * bfhi(u0) + e1 * bfhi(u1) + e2 * bfhi(u2) + e3 * bfhi(u3);
    }
    for (; i < d; i++) {
        int s0 = csr_src[start + i];
        float as0 = a1s[s0 * 8 + h];
        unsigned int u0 = *(const unsigned int*)(h1b + (size_t)s0 * 128 + lane * 2);
        float e0 = __expf(lrelu(as0 + ad));
        l += e0;
        acc0 += e0 * bflo(u0);
        acc1 += e0 * bfhi(u0);
    }
    float inv = 1.f / (l + 1e-16f);
    float v0 = acc0 * inv + b1[lane * 2];
    float v1 = acc1 * inv + b1[lane * 2 + 1];
    v0 = (v0 > 0.f) ? v0 : expm1f(v0);
    v1 = (v1 > 0.f) ? v1 : expm1f(v1);
    h2b[(size_t)node * 64 + lane] = (unsigned int)f2bf(v0) | ((unsigned int)f2bf(v1) << 16);
}

// ---------------------------------------------------------------------------
// GEMM2 (MFMA bf16): t2b = bf16(h2[N,128] @ W2[128,64]); fused a2s/a2d dots.
// ---------------------------------------------------------------------------
__global__ void __launch_bounds__(256) gemm2_kernel(
        const short8* __restrict__ h2f, const short8* __restrict__ w2b,
        const float* __restrict__ att_s, const float* __restrict__ att_d,
        unsigned short* __restrict__ t2b, float* __restrict__ a2s, float* __restrict__ a2d,
        int n) {
    const int lane = threadIdx.x & 63;
    const int wv = threadIdx.x >> 6;
    const int quad = lane >> 4;
    const int l15 = lane & 15;

    const int rowA = blockIdx.x * 64 + wv * 16 + l15;
    const bool rowAok = rowA < n;

    floatx4 acc[4];
    #pragma unroll
    for (int t = 0; t < 4; t++) acc[t] = (floatx4){0.f, 0.f, 0.f, 0.f};

    #pragma unroll
    for (int ks = 0; ks < 4; ks++) {
        short8 af = {0, 0, 0, 0, 0, 0, 0, 0};
        if (rowAok) af = h2f[(size_t)rowA * 16 + ks * 4 + quad];
        #pragma unroll
        for (int t = 0; t < 4; t++) {
            short8 bf = w2b[(t * 4 + ks) * 64 + lane];
            acc[t] = __builtin_amdgcn_mfma_f32_16x16x32_bf16(af, bf, acc[t], 0, 0, 0);
        }
    }

    const int rowC0 = blockIdx.x * 64 + wv * 16 + quad * 4;
    float asw[4], adw[4];
    #pragma unroll
    for (int t = 0; t < 4; t++) {
        asw[t] = att_s[t * 16 + l15];
        adw[t] = att_d[t * 16 + l15];
    }
    #pragma unroll
    for (int r = 0; r < 4; r++) {
        int grow = rowC0 + r;
        bool ok = grow < n;
        float ps = 0.f, pd = 0.f;
        #pragma unroll
        for (int t = 0; t < 4; t++) {
            float c = acc[t][r];
            if (ok) t2b[(size_t)grow * 64 + t * 16 + l15] = f2bf(c);
            ps += c * asw[t];
            pd += c * adw[t];
        }
        ps += __shfl_xor(ps, 1, 64); ps += __shfl_xor(ps, 2, 64);
        ps += __shfl_xor(ps, 4, 64); ps += __shfl_xor(ps, 8, 64);
        pd += __shfl_xor(pd, 1, 64); pd += __shfl_xor(pd, 2, 64);
        pd += __shfl_xor(pd, 4, 64); pd += __shfl_xor(pd, 8, 64);
        if (l15 == 0 && ok) { a2s[grow] = ps; a2d[grow] = pd; }
    }
}

// ---------------------------------------------------------------------------
// agg2: one wave per dst node over CSR, 4-way unrolled, bf16 t2 gather.
// Fused bias + log_softmax across the 64 lanes.
// ---------------------------------------------------------------------------
__global__ void __launch_bounds__(256) agg2_kernel(
        const unsigned short* __restrict__ t2b, const float* __restrict__ a2s,
        const float* __restrict__ a2d, const int* __restrict__ rowstart,
        const int* __restrict__ deg, const int* __restrict__ csr_src,
        const float* __restrict__ b2, float* __restrict__ out, int n) {
    const int lane = threadIdx.x & 63;
    const int node = blockIdx.x * 4 + (threadIdx.x >> 6);
    if (node >= n) return;
    const int start = rowstart[node];
    const int d = deg[node];
    const float ad = a2d[node];
    float l = 0.f, acc = 0.f;
    int i = 0;
    for (; i + 4 <= d; i += 4) {
        int s0 = csr_src[start + i];
        int s1 = csr_src[start + i + 1];
        int s2 = csr_src[start + i + 2];
        int s3 = csr_src[start + i + 3];
        float as0 = a2s[s0];
        float as1 = a2s[s1];
        float as2 = a2s[s2];
        float as3 = a2s[s3];
        unsigned short u0 = t2b[(size_t)s0 * 64 + lane];
        unsigned short u1 = t2b[(size_t)s1 * 64 + lane];
        unsigned short u2 = t2b[(size_t)s2 * 64 + lane];
        unsigned short u3 = t2b[(size_t)s3 * 64 + lane];
        float e0 = __expf(lrelu(as0 + ad));
        float e1 = __expf(lrelu(as1 + ad));
        float e2 = __expf(lrelu(as2 + ad));
        float e3 = __expf(lrelu(as3 + ad));
        l += (e0 + e1) + (e2 + e3);
        acc += e0 * __uint_as_float(((unsigned int)u0) << 16)
             + e1 * __uint_as_float(((unsigned int)u1) << 16)
             + e2 * __uint_as_float(((unsigned int)u2) << 16)
             + e3 * __uint_as_float(((unsigned int)u3) << 16);
    }
    for (; i < d; i++) {
        int s0 = csr_src[start + i];
        float as0 = a2s[s0];
        unsigned short u0 = t2b[(size_t)s0 * 64 + lane];
        float e0 = __expf(lrelu(as0 + ad));
        l += e0;
        acc += e0 * __uint_as_float(((unsigned int)u0) << 16);
    }
    float v = acc / (l + 1e-16f) + b2[lane];
    float mx = v;
    #pragma unroll
    for (int off = 32; off >= 1; off >>= 1) mx = fmaxf(mx, __shfl_xor(mx, off, 64));
    float ex = expf(v - mx);
    float s2 = ex;
    #pragma unroll
    for (int off = 32; off >= 1; off >>= 1) s2 += __shfl_xor(s2, off, 64);
    out[(size_t)node * 64 + lane] = v - mx - logf(s2);
}

// ---------------------------------------------------------------------------

extern "C" void kernel_launch(void* const* d_in, const int* in_sizes, int n_in,
                              void* d_out, int out_size, void* d_ws, size_t ws_size,
                              hipStream_t stream) {
    const float* x     = (const float*)d_in[0];
    const int*   ei    = (const int*)d_in[1];
    const float* W1    = (const float*)d_in[2];
    const float* att1s = (const float*)d_in[3];
    const float* att1d = (const float*)d_in[4];
    const float* b1    = (const float*)d_in[5];
    const float* W2    = (const float*)d_in[6];
    const float* att2s = (const float*)d_in[7];
    const float* att2d = (const float*)d_in[8];
    const float* b2    = (const float*)d_in[9];
    float* out = (float*)d_out;

    const int N = N_NODES, E = N_EDGES;

    char* p = (char*)d_ws;
    auto take = [&](size_t bytes) {
        char* r = p;
        p += (bytes + 255) & ~(size_t)255;
        return (void*)r;
    };
    int*            head     = (int*)take((size_t)N * 4);
    int*            deg      = (int*)take((size_t)N * 4);
    int*            rowstart = (int*)take((size_t)N * 4);
    int*            counter  = (int*)take(256);
    int2*           rec8     = (int2*)take((size_t)E * 8);
    int*            csr_src  = (int*)take((size_t)E * 4);
    unsigned short* w1b      = (unsigned short*)take(64 * 64 * 16);           // 64 KB
    unsigned short* w2b      = (unsigned short*)take(16 * 64 * 16);           // 16 KB
    unsigned short* h1b      = (unsigned short*)take((size_t)N * 128 * 2);    // bf16
    float*          a1s      = (float*)take((size_t)N * 8 * 4);               // reused a2s
    float*          a1d      = (float*)take((size_t)N * 8 * 4);               // reused a2d
    unsigned int*   h2b      = (unsigned int*)take((size_t)N * 64 * 4);       // packed bf16
    unsigned short* t2b      = (unsigned short*)take((size_t)N * 64 * 2);     // bf16
    float* a2s = a1s;
    float* a2d = a1d;

    hipMemsetAsync(head, 0xFF, (size_t)N * 4, stream);   // -1 sentinels
    hipMemsetAsync(counter, 0, 4, stream);

    prep_kernel<<<20, 256, 0, stream>>>(W1, W2, w1b, w2b);
    gemm1_link_kernel<<<FUSED_BLOCKS, 256, 0, stream>>>(
        x, (const short8*)w1b, att1s, att1d, h1b, a1s, a1d, ei, head, rec8);
    count_alloc_kernel<<<(N + 255) / 256, 256, 0, stream>>>(head, rec8, rowstart, deg,
                                                            counter, N);
    flatten_kernel<<<(N + 255) / 256, 256, 0, stream>>>(head, rec8, rowstart, csr_src, N);
    agg1_kernel<<<(N + 3) / 4, 256, 0, stream>>>(h1b, a1s, a1d, rowstart, deg, csr_src,
                                                 b1, h2b, N);
    gemm2_kernel<<<(N + 63) / 64, 256, 0, stream>>>((const short8*)h2b, (const short8*)w2b,
                                                    att2s, att2d, t2b, a2s, a2d, N);
    agg2_kernel<<<(N + 3) / 4, 256, 0, stream>>>(t2b, a2s, a2d, rowstart, deg, csr_src,
                                                 b2, out, N);
}